// Round 13
// baseline (4212.994 us; speedup 1.0000x reference)
//
#include <hip/hip_runtime.h>

#define B_   2048
#define T_   120
#define E_   144
#define L_   4
#define NH_  8
#define HD_  18
#define FF_  576
#define H_   144
#define GIN_ 288
#define TH_  432
#define FUT_ 24
#define BT_  (B_*T_)

typedef unsigned short u16;
typedef unsigned int   u32;

typedef __attribute__((ext_vector_type(8))) short short8v;
typedef __attribute__((ext_vector_type(4))) float f32x4;

__device__ __forceinline__ float bf2f(u16 u) {
    u32 x = ((u32)u) << 16;
    return __uint_as_float(x);
}
__device__ __forceinline__ u16 f2bf(float f) {
    u32 x = __float_as_uint(f);
    u32 r = (x + 0x7fffu + ((x >> 16) & 1u)) >> 16;
    return (u16)r;
}

struct F4 { float x, y, z, w; };
__device__ __forceinline__ F4 load4(const float* p) {
    float4 v = *(const float4*)p;
    return {v.x, v.y, v.z, v.w};
}
__device__ __forceinline__ void store1(float* p, float v) { *p = v; }
__device__ __forceinline__ void store1(u16* p, float v)   { *p = f2bf(v); }

// packed-fragment weight load: wave-contiguous 1KB per instruction.
__device__ __forceinline__ short8v wfrag(const u16* Wp, int tile, int NS, int s, int l) {
    return *(const short8v*)(Wp + (((size_t)tile * NS + s) * 64 + l) * 8);
}

__device__ __forceinline__ void gll16(const void* g, void* l) {
    __builtin_amdgcn_global_load_lds(
        (const __attribute__((address_space(1))) u32*)g,
        (__attribute__((address_space(3))) u32*)l, 16, 0, 0);
}

// masked q/k fragment from compact [row][440] layout: head cols colbase..colbase+17,
// MFMA k-dim padded to 32 with zeros via compile-time lane-group masks.
__device__ __forceinline__ short8v qk_frag(const u16* rowp, int colbase, int lg) {
    u32 u0 = 0, u1 = 0, u2 = 0, u3 = 0;
    const u32* p = (const u32*)(rowp + colbase + lg * 8);
    if (lg < 2) { u0 = p[0]; u1 = p[1]; u2 = p[2]; u3 = p[3]; }
    else if (lg == 2) { u0 = p[0]; }
    union { u32 u[4]; short8v v; } r;
    r.u[0] = u0; r.u[1] = u1; r.u[2] = u2; r.u[3] = u3;
    return r.v;
}

// ---------------- weight pack: f32 [rows x sstr] -> bf16 MFMA-fragment order ----
__global__ void wpack_kernel(const float* __restrict__ src, u16* __restrict__ dst,
                             int ntiles, int NS, int K, int sstr)
{
    int i = blockIdx.x * 256 + threadIdx.x;
    if (i >= ntiles * NS * 512) return;
    int e  = i & 7;
    int l  = (i >> 3) & 63;
    int c  = i >> 9;
    int s  = c % NS;
    int tile = c / NS;
    int li = l & 15, lg = l >> 4;
    int row = tile * 16 + li;
    int k   = s * 32 + lg * 8 + e;
    dst[i] = (k < K) ? f2bf(src[(size_t)row * sstr + k]) : (u16)0;
}

__global__ void cast_bf_kernel(const float* __restrict__ src, u16* __restrict__ dst,
                               int n2)
{
    int i = blockIdx.x * 256 + threadIdx.x;
    if (i >= n2) return;
    float2 t = ((const float2*)src)[i];
    ((u32*)dst)[i] = ((u32)f2bf(t.y) << 16) | (u32)f2bf(t.x);
}

// ======== whole transformer layer, one block per sample =========================
// 256 thr = 4 waves. LDS: X-area 43008B (staging / P / lnS,lnQ / Fls) + QKV 112640B.
template<bool RESF32, bool WF32>
__global__ __launch_bounds__(256, 1) void layer_kernel(
    const u16* __restrict__ xin,
    const float* __restrict__ resf, const u16* __restrict__ resb,
    const u16* __restrict__ Wqkv, const float* __restrict__ bqkv,
    const u16* __restrict__ Wo, const float* __restrict__ bo,
    const float* __restrict__ ln1w, const float* __restrict__ ln1b,
    const u16* __restrict__ W1, const float* __restrict__ b1,
    const u16* __restrict__ W2, const float* __restrict__ b2,
    const float* __restrict__ ln2w, const float* __restrict__ ln2b,
    u16* __restrict__ obf, float* __restrict__ of)
{
    __shared__ __align__(16) u16 Xls[21504];       // 43008 B
    __shared__ __align__(16) u16 QKV[128 * 440];   // 112640 B

    const int tid = threadIdx.x;
    const int w  = tid >> 6, l = tid & 63;
    const int lg = l >> 4,  li = l & 15;
    const size_t grow0 = (size_t)blockIdx.x * T_;

    // zero X rows 120..127 (so padded GEMM rows stay finite)
    for (int i = tid; i < 672; i += 256) ((u32*)Xls)[10080 + i] = 0;
    // stage x: 120 rows x 18 chunks (LDS rows stride 21 chunks, cols 18..20 dup 17)
    {
        const char* src = (const char*)(xin + grow0 * E_);
        char* dst = (char*)Xls;
#pragma unroll
        for (int i = 0; i < 10; ++i) {
            int inst = w * 10 + i;
            int chunk = inst * 64 + l;
            if (chunk < 2520) {
                int row = chunk / 21, col = chunk - row * 21;
                if (col > 17) col = 17;
                gll16(src + row * 288 + col * 16, dst + inst * 1024);
            }
        }
    }
    __syncthreads();

    // ---- phase 1: qkv GEMM (X @ Wqkv^T + b) -> QKV bf16 ----
#pragma unroll
    for (int ci = 0; ci < 7; ++ci) {
        int ct = w + 4 * ci;
        if (ct < 27) {
            f32x4 acc[8];
#pragma unroll
            for (int rt = 0; rt < 8; ++rt) acc[rt] = {0.f, 0.f, 0.f, 0.f};
#pragma unroll
            for (int s = 0; s < 5; ++s) {
                short8v bf = wfrag(Wqkv, ct, 5, s, l);
#pragma unroll
                for (int rt = 0; rt < 8; ++rt) {
                    short8v af = *(const short8v*)(Xls + (rt * 16 + li) * 168 + s * 32 + lg * 8);
                    acc[rt] = __builtin_amdgcn_mfma_f32_16x16x32_bf16(af, bf, acc[rt], 0, 0, 0);
                }
            }
            int col = ct * 16 + li;
            float bv = bqkv[col];
#pragma unroll
            for (int rt = 0; rt < 8; ++rt)
#pragma unroll
                for (int j = 0; j < 4; ++j)
                    QKV[(rt * 16 + lg * 4 + j) * 440 + col] = f2bf(acc[rt][j] + bv);
        }
    }
    __syncthreads();

    // ---- phase 2: attention (no internal barriers; wave owns qtiles 2w,2w+1) ----
    {
        const float scale = 0.23570226039551584f; // 1/sqrt(18)
        u16* Pw = Xls + w * 2176;                 // 16 x 136 per wave
        for (int h = 0; h < NH_; ++h) {
            const int qc = h * HD_;
            // hoist k-frags and v-frags for this head
            short8v kf[8];
#pragma unroll
            for (int nt = 0; nt < 8; ++nt)
                kf[nt] = qk_frag(QKV + (nt * 16 + li) * 440, E_ + qc, lg);
            short8v vf[2][4];
#pragma unroll
            for (int dt = 0; dt < 2; ++dt) {
                int d = dt * 16 + li;
#pragma unroll
                for (int s = 0; s < 4; ++s) {
                    union { u16 h16[8]; short8v v; } r;
#pragma unroll
                    for (int e = 0; e < 8; ++e)
                        r.h16[e] = (d < HD_)
                            ? QKV[(s * 32 + lg * 8 + e) * 440 + 2 * E_ + qc + d]
                            : (u16)0;
                    vf[dt][s] = r.v;
                }
            }
#pragma unroll
            for (int qi = 0; qi < 2; ++qi) {
                int qt = 2 * w + qi;
                short8v qf = qk_frag(QKV + (qt * 16 + li) * 440, qc, lg);
                f32x4 sacc[8];
#pragma unroll
                for (int nt = 0; nt < 8; ++nt) sacc[nt] = {0.f, 0.f, 0.f, 0.f};
#pragma unroll
                for (int nt = 0; nt < 8; ++nt)
                    sacc[nt] = __builtin_amdgcn_mfma_f32_16x16x32_bf16(qf, kf[nt], sacc[nt], 0, 0, 0);

                float invl[4];
#pragma unroll
                for (int j = 0; j < 4; ++j) {
                    float v[8];
                    float m = -1e30f;
#pragma unroll
                    for (int nt = 0; nt < 8; ++nt) {
                        float s = sacc[nt][j] * scale;
                        if (nt == 7 && li >= 8) s = -1e30f;   // t >= 120
                        v[nt] = s;
                        m = fmaxf(m, s);
                    }
#pragma unroll
                    for (int off = 1; off < 16; off <<= 1)
                        m = fmaxf(m, __shfl_xor(m, off));
                    float sum = 0.f;
#pragma unroll
                    for (int nt = 0; nt < 8; ++nt) {
                        float p = __expf(v[nt] - m);
                        sum += p;
                        Pw[(lg * 4 + j) * 136 + nt * 16 + li] = f2bf(p);
                    }
#pragma unroll
                    for (int off = 1; off < 16; off <<= 1)
                        sum += __shfl_xor(sum, off);
                    invl[j] = 1.f / sum;
                }

                f32x4 oacc[2] = {{0.f,0.f,0.f,0.f},{0.f,0.f,0.f,0.f}};
#pragma unroll
                for (int s = 0; s < 4; ++s) {
                    short8v pf = *(const short8v*)(Pw + li * 136 + s * 32 + lg * 8);
#pragma unroll
                    for (int dt = 0; dt < 2; ++dt)
                        oacc[dt] = __builtin_amdgcn_mfma_f32_16x16x32_bf16(pf, vf[dt][s], oacc[dt], 0, 0, 0);
                }
                // ob write in-place over q-region (own rows; head h's q cols now dead)
#pragma unroll
                for (int dt = 0; dt < 2; ++dt) {
                    int d = dt * 16 + li;
                    if (d < HD_) {
#pragma unroll
                        for (int j = 0; j < 4; ++j)
                            QKV[(qt * 16 + lg * 4 + j) * 440 + qc + d] =
                                f2bf(oacc[dt][j] * invl[j]);
                    }
                }
            }
        }
    }
    __syncthreads();

    float* lnS = (float*)(Xls + 10240);   // [4][128]
    float* lnQ = (float*)(Xls + 11264);   // [4][128]

    // ---- phase 3: out-proj + bias + residual -> LN1 ----
    float rr[3][8][4];
#pragma unroll
    for (int ci = 0; ci < 3; ++ci) {
        int tile = w + 4 * ci;
        if (tile < 9) {
            int col = tile * 16 + li;
#pragma unroll
            for (int rt = 0; rt < 8; ++rt)
#pragma unroll
                for (int j = 0; j < 4; ++j) {
                    int r = rt * 16 + lg * 4 + j;
                    if (r > 119) r = 119;
                    rr[ci][rt][j] = RESF32 ? resf[(grow0 + r) * E_ + col]
                                           : bf2f(resb[(grow0 + r) * E_ + col]);
                }
        }
    }

    f32x4 acc[3][8];
#pragma unroll
    for (int ci = 0; ci < 3; ++ci)
#pragma unroll
        for (int rt = 0; rt < 8; ++rt) acc[ci][rt] = {0.f, 0.f, 0.f, 0.f};
#pragma unroll
    for (int s = 0; s < 5; ++s) {
        short8v bfv[3];
#pragma unroll
        for (int ci = 0; ci < 3; ++ci) {
            int tile = w + 4 * ci;
            if (tile < 9) bfv[ci] = wfrag(Wo, tile, 5, s, l);
        }
#pragma unroll
        for (int rt = 0; rt < 8; ++rt) {
            short8v af = *(const short8v*)(QKV + (rt * 16 + li) * 440 + s * 32 + lg * 8);
#pragma unroll
            for (int ci = 0; ci < 3; ++ci)
                if (w + 4 * ci < 9)
                    acc[ci][rt] = __builtin_amdgcn_mfma_f32_16x16x32_bf16(af, bfv[ci], acc[ci][rt], 0, 0, 0);
        }
    }

    float vv[3][8][4];
#pragma unroll
    for (int ci = 0; ci < 3; ++ci) {
        int tile = w + 4 * ci;
        if (tile < 9) {
            float bv = bo[tile * 16 + li];
#pragma unroll
            for (int rt = 0; rt < 8; ++rt)
#pragma unroll
                for (int j = 0; j < 4; ++j)
                    vv[ci][rt][j] = acc[ci][rt][j] + bv + rr[ci][rt][j];
        }
    }
    // LN1 reduce (cross-wave)
#pragma unroll
    for (int rt = 0; rt < 8; ++rt)
#pragma unroll
        for (int j = 0; j < 4; ++j) {
            float s = 0.f, q = 0.f;
#pragma unroll
            for (int ci = 0; ci < 3; ++ci)
                if (w + 4 * ci < 9) { s += vv[ci][rt][j]; q += vv[ci][rt][j] * vv[ci][rt][j]; }
#pragma unroll
            for (int off = 1; off < 16; off <<= 1) {
                s += __shfl_xor(s, off);
                q += __shfl_xor(q, off);
            }
            if (li == 0) {
                lnS[w * 128 + rt * 16 + lg * 4 + j] = s;
                lnQ[w * 128 + rt * 16 + lg * 4 + j] = q;
            }
        }
    __syncthreads();
#pragma unroll
    for (int rt = 0; rt < 8; ++rt)
#pragma unroll
        for (int j = 0; j < 4; ++j) {
            int r = rt * 16 + lg * 4 + j;
            float s = lnS[r] + lnS[128 + r] + lnS[256 + r] + lnS[384 + r];
            float q = lnQ[r] + lnQ[128 + r] + lnQ[256 + r] + lnQ[384 + r];
            float mean = s * (1.f / 144.f);
            float var  = q * (1.f / 144.f) - mean * mean;
            float rstd = rsqrtf(var + 1e-5f);
#pragma unroll
            for (int ci = 0; ci < 3; ++ci) {
                int tile = w + 4 * ci;
                if (tile < 9) {
                    int col = tile * 16 + li;
                    float o = (vv[ci][rt][j] - mean) * rstd * ln1w[col] + ln1b[col];
                    vv[ci][rt][j] = o;                     // FFN residual (f32)
                    QKV[r * 440 + col] = f2bf(o);          // FFN input (bf16)
                }
            }
        }
    __syncthreads();

    // ---- phase 4: FFN (9 chunks of 64 ff cols; Fls in dead X-area) ----
    u16* Fls = Xls;   // [128][72]
    f32x4 acc2[3][8];
#pragma unroll
    for (int ci = 0; ci < 3; ++ci)
#pragma unroll
        for (int rt = 0; rt < 8; ++rt) acc2[ci][rt] = {0.f, 0.f, 0.f, 0.f};

    for (int c = 0; c < 9; ++c) {
        f32x4 acc1[8];
#pragma unroll
        for (int rt = 0; rt < 8; ++rt) acc1[rt] = {0.f, 0.f, 0.f, 0.f};
#pragma unroll
        for (int s = 0; s < 5; ++s) {
            short8v bf = wfrag(W1, c * 4 + w, 5, s, l);
#pragma unroll
            for (int rt = 0; rt < 8; ++rt) {
                short8v af = *(const short8v*)(QKV + (rt * 16 + li) * 440 + s * 32 + lg * 8);
                acc1[rt] = __builtin_amdgcn_mfma_f32_16x16x32_bf16(af, bf, acc1[rt], 0, 0, 0);
            }
        }
        __syncthreads();   // prev chunk ffn2 reads complete
        {
            int colc = w * 16 + li;
            float bv = b1[c * 64 + colc];
#pragma unroll
            for (int rt = 0; rt < 8; ++rt)
#pragma unroll
                for (int j = 0; j < 4; ++j) {
                    float v = fmaxf(acc1[rt][j] + bv, 0.f);
                    Fls[(rt * 16 + lg * 4 + j) * 72 + colc] = f2bf(v);
                }
        }
        __syncthreads();
#pragma unroll
        for (int s2 = 0; s2 < 2; ++s2) {
            short8v bfw[3];
#pragma unroll
            for (int ci = 0; ci < 3; ++ci) {
                int tile = w + 4 * ci;
                if (tile < 9) bfw[ci] = wfrag(W2, tile, 18, c * 2 + s2, l);
            }
#pragma unroll
            for (int rt = 0; rt < 8; ++rt) {
                short8v pf = *(const short8v*)(Fls + (rt * 16 + li) * 72 + s2 * 32 + lg * 8);
#pragma unroll
                for (int ci = 0; ci < 3; ++ci)
                    if (w + 4 * ci < 9)
                        acc2[ci][rt] = __builtin_amdgcn_mfma_f32_16x16x32_bf16(pf, bfw[ci], acc2[ci][rt], 0, 0, 0);
            }
        }
    }

    // ---- epilogue: + b2 + res2 -> LN2 -> global writes ----
#pragma unroll
    for (int ci = 0; ci < 3; ++ci) {
        int tile = w + 4 * ci;
        if (tile < 9) {
            float bv = b2[tile * 16 + li];
#pragma unroll
            for (int rt = 0; rt < 8; ++rt)
#pragma unroll
                for (int j = 0; j < 4; ++j)
                    vv[ci][rt][j] = acc2[ci][rt][j] + bv + vv[ci][rt][j];
        }
    }
    __syncthreads();   // lnS reuse
#pragma unroll
    for (int rt = 0; rt < 8; ++rt)
#pragma unroll
        for (int j = 0; j < 4; ++j) {
            float s = 0.f, q = 0.f;
#pragma unroll
            for (int ci = 0; ci < 3; ++ci)
                if (w + 4 * ci < 9) { s += vv[ci][rt][j]; q += vv[ci][rt][j] * vv[ci][rt][j]; }
#pragma unroll
            for (int off = 1; off < 16; off <<= 1) {
                s += __shfl_xor(s, off);
                q += __shfl_xor(q, off);
            }
            if (li == 0) {
                lnS[w * 128 + rt * 16 + lg * 4 + j] = s;
                lnQ[w * 128 + rt * 16 + lg * 4 + j] = q;
            }
        }
    __syncthreads();
#pragma unroll
    for (int rt = 0; rt < 8; ++rt)
#pragma unroll
        for (int j = 0; j < 4; ++j) {
            int r = rt * 16 + lg * 4 + j;
            if (r < T_) {
                float s = lnS[r] + lnS[128 + r] + lnS[256 + r] + lnS[384 + r];
                float q = lnQ[r] + lnQ[128 + r] + lnQ[256 + r] + lnQ[384 + r];
                float mean = s * (1.f / 144.f);
                float var  = q * (1.f / 144.f) - mean * mean;
                float rstd = rsqrtf(var + 1e-5f);
#pragma unroll
                for (int ci = 0; ci < 3; ++ci) {
                    int tile = w + 4 * ci;
                    if (tile < 9) {
                        int col = tile * 16 + li;
                        float o = (vv[ci][rt][j] - mean) * rstd * ln2w[col] + ln2b[col];
                        obf[(grow0 + r) * E_ + col] = f2bf(o);
                        if (WF32) of[(grow0 + r) * E_ + col] = o;
                    }
                }
            }
        }
}

// ---------------- f32 GEMM (small, ctx path) ------------------------------------
template<typename AT, typename OT, bool BIAS, bool RELU, bool RES>
__global__ __launch_bounds__(256) void gemm_kernel(
    const AT* __restrict__ A, const float* __restrict__ W, int ldw,
    const float* __restrict__ bias, const float* __restrict__ res,
    OT* __restrict__ C, int M, int N, int K)
{
    constexpr int BM = 64, BN = 64, BK = 16;
    __shared__ float As[BK][BM + 4];
    __shared__ float Ws[BK][BN + 4];
    const int tid = threadIdx.x;
    const int bm = blockIdx.y * BM;
    const int bn = blockIdx.x * BN;
    const int tx = tid & 15, ty = tid >> 4;
    const int lr = tid >> 2;
    const int lc = (tid & 3) << 2;

    float acc[4][4];
#pragma unroll
    for (int i = 0; i < 4; i++)
#pragma unroll
        for (int j = 0; j < 4; j++) acc[i][j] = 0.f;

    for (int k0 = 0; k0 < K; k0 += BK) {
        F4 av = load4(A + (size_t)(bm + lr) * K + k0 + lc);
        As[lc + 0][lr] = av.x; As[lc + 1][lr] = av.y;
        As[lc + 2][lr] = av.z; As[lc + 3][lr] = av.w;
        int n = bn + lr;
        F4 wv = {0.f, 0.f, 0.f, 0.f};
        if (n < N) {
            float4 t = *(const float4*)(W + (size_t)n * ldw + k0 + lc);
            wv = {t.x, t.y, t.z, t.w};
        }
        Ws[lc + 0][lr] = wv.x; Ws[lc + 1][lr] = wv.y;
        Ws[lc + 2][lr] = wv.z; Ws[lc + 3][lr] = wv.w;
        __syncthreads();
#pragma unroll
        for (int kk = 0; kk < BK; ++kk) {
            float a[4], wr[4];
#pragma unroll
            for (int i = 0; i < 4; i++) a[i] = As[kk][ty * 4 + i];
#pragma unroll
            for (int j = 0; j < 4; j++) wr[j] = Ws[kk][tx * 4 + j];
#pragma unroll
            for (int i = 0; i < 4; i++)
#pragma unroll
                for (int j = 0; j < 4; j++) acc[i][j] += a[i] * wr[j];
        }
        __syncthreads();
    }
#pragma unroll
    for (int i = 0; i < 4; i++) {
        int m = bm + ty * 4 + i;
#pragma unroll
        for (int j = 0; j < 4; j++) {
            int n = bn + tx * 4 + j;
            if (n < N) {
                float v = acc[i][j];
                if (BIAS) v += bias[n];
                if (RES)  v += res[(size_t)m * N + n];
                if (RELU) v = fmaxf(v, 0.f);
                store1(&C[(size_t)m * N + n], v);
            }
        }
    }
}

// ---------------- mean over T ----------------------------------------------------
__global__ void mean_kernel(const float* __restrict__ x, float* __restrict__ out,
                            int nb)
{
    int idx = blockIdx.x * blockDim.x + threadIdx.x;
    if (idx >= nb * E_) return;
    int b = idx / E_, e = idx % E_;
    const float* p = x + (size_t)b * T_ * E_ + e;
    float s = 0.f;
    for (int t = 0; t < T_; t++) s += p[(size_t)t * E_];
    out[idx] = s * (1.f / 120.f);
}

__device__ __forceinline__ float sigmoidf_(float x) {
    return 1.f / (1.f + __expf(-x));
}

// ======== persistent GRU decode =================================================
#define GRU_M 16
__global__ __launch_bounds__(192) void gru_all_kernel(
    const float* __restrict__ seed,
    const float* __restrict__ gctx,
    const u16* __restrict__ WxB,
    const u16* __restrict__ WhB,
    const u16* __restrict__ SpB,
    const float* __restrict__ b_hh,
    const float* __restrict__ spl_b,
    float* __restrict__ out)
{
    __shared__ __align__(16) u16 xls[GRU_M * 168];
    __shared__ __align__(16) u16 hls[GRU_M * 168];

    const int tid = threadIdx.x;
    const int w = tid >> 6, l = tid & 63;
    const int lg = l >> 4, li = l & 15;
    const int b0 = blockIdx.x * GRU_M;
    const int fr = w * 48 + li;

    for (int i = tid; i < GRU_M * 84; i += 192) {
        ((u32*)xls)[i] = 0; ((u32*)hls)[i] = 0;
    }
    __syncthreads();
    for (int i = tid; i < GRU_M * 72; i += 192) {
        int r = i / 72, e2 = i - r * 72;
        float2 t = *(const float2*)(seed + (size_t)(b0 + r) * T_ * E_
                                    + (size_t)(T_ - 1) * E_ + 2 * e2);
        ((u32*)(xls + r * 168))[e2] = ((u32)f2bf(t.y) << 16) | (u32)f2bf(t.x);
    }

    float gctxv[3][3][4];
    float bhh[3][3];
    float splb[3];
#pragma unroll
    for (int g = 0; g < 3; ++g)
#pragma unroll
        for (int ct = 0; ct < 3; ++ct) {
            int f = g * 144 + fr + ct * 16;
            bhh[g][ct] = b_hh[f];
#pragma unroll
            for (int j = 0; j < 4; ++j)
                gctxv[g][ct][j] = gctx[(size_t)(b0 + lg * 4 + j) * TH_ + f];
        }
#pragma unroll
    for (int ct = 0; ct < 3; ++ct) splb[ct] = spl_b[fr + ct * 16];

    float hold[3][4];
#pragma unroll
    for (int ct = 0; ct < 3; ++ct)
#pragma unroll
        for (int j = 0; j < 4; ++j) hold[ct][j] = 0.f;

    __syncthreads();

    for (int st = 0; st < FUT_; ++st) {
        f32x4 aRZ[2][3], aNi[3], aNh[3];
#pragma unroll
        for (int g = 0; g < 2; ++g)
#pragma unroll
            for (int ct = 0; ct < 3; ++ct) aRZ[g][ct] = {0.f, 0.f, 0.f, 0.f};
#pragma unroll
        for (int ct = 0; ct < 3; ++ct) {
            aNi[ct] = {0.f, 0.f, 0.f, 0.f};
            aNh[ct] = {0.f, 0.f, 0.f, 0.f};
        }
#pragma unroll
        for (int s = 0; s < 5; ++s) {
            short8v ax = *(const short8v*)(xls + li * 168 + s * 32 + lg * 8);
            short8v ah = *(const short8v*)(hls + li * 168 + s * 32 + lg * 8);
#pragma unroll
            for (int ct = 0; ct < 3; ++ct) {
#pragma unroll
                for (int g = 0; g < 2; ++g) {
                    int tile = g * 9 + w * 3 + ct;
                    short8v bx = wfrag(WxB, tile, 5, s, l);
                    aRZ[g][ct] = __builtin_amdgcn_mfma_f32_16x16x32_bf16(ax, bx, aRZ[g][ct], 0, 0, 0);
                    short8v bh = wfrag(WhB, tile, 5, s, l);
                    aRZ[g][ct] = __builtin_amdgcn_mfma_f32_16x16x32_bf16(ah, bh, aRZ[g][ct], 0, 0, 0);
                }
                int tile2 = 18 + w * 3 + ct;
                short8v bx2 = wfrag(WxB, tile2, 5, s, l);
                aNi[ct] = __builtin_amdgcn_mfma_f32_16x16x32_bf16(ax, bx2, aNi[ct], 0, 0, 0);
                short8v bh2 = wfrag(WhB, tile2, 5, s, l);
                aNh[ct] = __builtin_amdgcn_mfma_f32_16x16x32_bf16(ah, bh2, aNh[ct], 0, 0, 0);
            }
        }
        __syncthreads();
#pragma unroll
        for (int ct = 0; ct < 3; ++ct)
#pragma unroll
            for (int j = 0; j < 4; ++j) {
                float r = sigmoidf_(aRZ[0][ct][j] + gctxv[0][ct][j] + bhh[0][ct]);
                float z = sigmoidf_(aRZ[1][ct][j] + gctxv[1][ct][j] + bhh[1][ct]);
                float n = tanhf(aNi[ct][j] + gctxv[2][ct][j]
                                + r * (aNh[ct][j] + bhh[2][ct]));
                float hv = (1.f - z) * n + z * hold[ct][j];
                hold[ct][j] = hv;
                hls[(lg * 4 + j) * 168 + fr + ct * 16] = f2bf(hv);
            }
        __syncthreads();
        f32x4 aS[3];
#pragma unroll
        for (int ct = 0; ct < 3; ++ct) aS[ct] = {0.f, 0.f, 0.f, 0.f};
#pragma unroll
        for (int s = 0; s < 5; ++s) {
            short8v ah = *(const short8v*)(hls + li * 168 + s * 32 + lg * 8);
#pragma unroll
            for (int ct = 0; ct < 3; ++ct) {
                short8v bs = wfrag(SpB, w * 3 + ct, 5, s, l);
                aS[ct] = __builtin_amdgcn_mfma_f32_16x16x32_bf16(ah, bs, aS[ct], 0, 0, 0);
            }
        }
#pragma unroll
        for (int ct = 0; ct < 3; ++ct) {
            int col = fr + ct * 16;
#pragma unroll
            for (int j = 0; j < 4; ++j) {
                float rv = aS[ct][j] + splb[ct];
                out[(size_t)(b0 + lg * 4 + j) * (FUT_ * E_) + (size_t)st * E_ + col] = rv;
                xls[(lg * 4 + j) * 168 + col] = f2bf(rv);
            }
        }
        __syncthreads();
    }
}

// =================================================================================
extern "C" void kernel_launch(void* const* d_in, const int* in_sizes, int n_in,
                              void* d_out, int out_size, void* d_ws, size_t ws_size,
                              hipStream_t stream)
{
    const float* seed   = (const float*)d_in[0];
    const float* qkv_w  = (const float*)d_in[1];
    const float* qkv_b  = (const float*)d_in[2];
    const float* out_w  = (const float*)d_in[3];
    const float* out_b  = (const float*)d_in[4];
    const float* ln1_w  = (const float*)d_in[5];
    const float* ln1_b  = (const float*)d_in[6];
    const float* ffn1_w = (const float*)d_in[7];
    const float* ffn1_b = (const float*)d_in[8];
    const float* ffn2_w = (const float*)d_in[9];
    const float* ffn2_b = (const float*)d_in[10];
    const float* ln2_w  = (const float*)d_in[11];
    const float* ln2_b  = (const float*)d_in[12];
    const float* proj_w = (const float*)d_in[13];
    const float* proj_b = (const float*)d_in[14];
    const float* w_ih   = (const float*)d_in[15];
    const float* w_hh   = (const float*)d_in[16];
    const float* b_ih   = (const float*)d_in[17];
    const float* b_hh   = (const float*)d_in[18];
    const float* spl_w  = (const float*)d_in[19];
    const float* spl_b  = (const float*)d_in[20];

    const size_t qkvW_n  = (size_t)L_ * TH_ * 160;
    const size_t outW_n  = (size_t)L_ * E_ * 160;
    const size_t ffn1W_n = (size_t)L_ * FF_ * 160;
    const size_t ffn2W_n = (size_t)L_ * E_ * 576;
    const size_t wxW_n   = (size_t)TH_ * 160;
    const size_t whW_n   = (size_t)TH_ * 160;
    const size_t spW_n   = (size_t)E_ * 160;

    char* wsp = (char*)d_ws;
    u16*   xbf   = (u16*)wsp;   wsp += (size_t)BT_ * E_ * 2;
    float* xres  = (float*)wsp; wsp += (size_t)BT_ * E_ * 4;
    float* ctxm  = (float*)wsp; wsp += (size_t)B_ * E_ * 4;
    float* ctx   = (float*)wsp; wsp += (size_t)B_ * E_ * 4;
    float* gctx  = (float*)wsp; wsp += (size_t)B_ * TH_ * 4;
    u16* qkvWb   = (u16*)wsp;   wsp += qkvW_n * 2;
    u16* outWb   = (u16*)wsp;   wsp += outW_n * 2;
    u16* ffn1Wb  = (u16*)wsp;   wsp += ffn1W_n * 2;
    u16* ffn2Wb  = (u16*)wsp;   wsp += ffn2W_n * 2;
    u16* wxB     = (u16*)wsp;   wsp += wxW_n * 2;
    u16* whB     = (u16*)wsp;   wsp += whW_n * 2;
    u16* splWb   = (u16*)wsp;   wsp += spW_n * 2;

    wpack_kernel<<<(int)((qkvW_n + 255) / 256), 256, 0, stream>>>(qkv_w, qkvWb, L_ * 27, 5, 144, 144);
    wpack_kernel<<<(int)((outW_n + 255) / 256), 256, 0, stream>>>(out_w, outWb, L_ * 9, 5, 144, 144);
    wpack_kernel<<<(int)((ffn1W_n + 255) / 256), 256, 0, stream>>>(ffn1_w, ffn1Wb, L_ * 36, 5, 144, 144);
    wpack_kernel<<<(int)((ffn2W_n + 255) / 256), 256, 0, stream>>>(ffn2_w, ffn2Wb, L_ * 9, 18, 576, 576);
    wpack_kernel<<<(int)((wxW_n + 255) / 256), 256, 0, stream>>>(w_ih, wxB, 27, 5, 144, GIN_);
    wpack_kernel<<<(int)((whW_n + 255) / 256), 256, 0, stream>>>(w_hh, whB, 27, 5, 144, 144);
    wpack_kernel<<<(int)((spW_n + 255) / 256), 256, 0, stream>>>(spl_w, splWb, 9, 5, 144, 144);

    cast_bf_kernel<<<(BT_ * 72 + 255) / 256, 256, 0, stream>>>(seed, xbf, BT_ * 72);

    for (int l = 0; l < L_; l++) {
        const u16* Wq = qkvWb + (size_t)l * TH_ * 160;
        const u16* Wo = outWb + (size_t)l * E_ * 160;
        const u16* W1 = ffn1Wb + (size_t)l * FF_ * 160;
        const u16* W2 = ffn2Wb + (size_t)l * E_ * 576;
        if (l == 0) {
            layer_kernel<true, false><<<B_, 256, 0, stream>>>(
                xbf, seed, nullptr, Wq, qkv_b + (size_t)l * TH_,
                Wo, out_b + (size_t)l * E_,
                ln1_w + (size_t)l * E_, ln1_b + (size_t)l * E_,
                W1, ffn1_b + (size_t)l * FF_, W2, ffn2_b + (size_t)l * E_,
                ln2_w + (size_t)l * E_, ln2_b + (size_t)l * E_, xbf, nullptr);
        } else if (l < 3) {
            layer_kernel<false, false><<<B_, 256, 0, stream>>>(
                xbf, nullptr, xbf, Wq, qkv_b + (size_t)l * TH_,
                Wo, out_b + (size_t)l * E_,
                ln1_w + (size_t)l * E_, ln1_b + (size_t)l * E_,
                W1, ffn1_b + (size_t)l * FF_, W2, ffn2_b + (size_t)l * E_,
                ln2_w + (size_t)l * E_, ln2_b + (size_t)l * E_, xbf, nullptr);
        } else {
            layer_kernel<false, true><<<B_, 256, 0, stream>>>(
                xbf, nullptr, xbf, Wq, qkv_b + (size_t)l * TH_,
                Wo, out_b + (size_t)l * E_,
                ln1_w + (size_t)l * E_, ln1_b + (size_t)l * E_,
                W1, ffn1_b + (size_t)l * FF_, W2, ffn2_b + (size_t)l * E_,
                ln2_w + (size_t)l * E_, ln2_b + (size_t)l * E_, xbf, xres);
        }
    }

    auto grid = [](int M, int N) { return dim3((N + 63) / 64, M / 64); };
    mean_kernel<<<(B_ * E_ + 255) / 256, 256, 0, stream>>>(xres, ctxm, B_);
    gemm_kernel<float, float, true, false, false><<<grid(B_, E_), 256, 0, stream>>>(
        ctxm, proj_w, E_, proj_b, nullptr, ctx, B_, E_, E_);
    gemm_kernel<float, float, true, false, false><<<grid(B_, TH_), 256, 0, stream>>>(
        ctx, w_ih + E_, GIN_, b_ih, nullptr, gctx, B_, TH_, E_);

    gru_all_kernel<<<B_ / GRU_M, 192, 0, stream>>>(
        seed, gctx, wxB, whB, splWb, b_hh, spl_b, (float*)d_out);
}

// Round 14
// 2926.674 us; speedup vs baseline: 1.4395x; 1.4395x over previous
//
#include <hip/hip_runtime.h>

#define B_   2048
#define T_   120
#define E_   144
#define L_   4
#define NH_  8
#define HD_  18
#define FF_  576
#define H_   144
#define GIN_ 288
#define TH_  432
#define FUT_ 24
#define BT_  (B_*T_)

typedef unsigned short u16;
typedef unsigned int   u32;

typedef __attribute__((ext_vector_type(8))) short short8v;
typedef __attribute__((ext_vector_type(4))) float f32x4;

__device__ __forceinline__ float bf2f(u16 u) {
    u32 x = ((u32)u) << 16;
    return __uint_as_float(x);
}
__device__ __forceinline__ u16 f2bf(float f) {
    u32 x = __float_as_uint(f);
    u32 r = (x + 0x7fffu + ((x >> 16) & 1u)) >> 16;
    return (u16)r;
}

struct F4 { float x, y, z, w; };
__device__ __forceinline__ F4 load4(const float* p) {
    float4 v = *(const float4*)p;
    return {v.x, v.y, v.z, v.w};
}
__device__ __forceinline__ void store1(float* p, float v) { *p = v; }
__device__ __forceinline__ void store1(u16* p, float v)   { *p = f2bf(v); }

// packed-fragment weight load: wave-contiguous 1KB per instruction.
__device__ __forceinline__ short8v wfrag(const u16* Wp, int tile, int NS, int s, int l) {
    return *(const short8v*)(Wp + (((size_t)tile * NS + s) * 64 + l) * 8);
}

__device__ __forceinline__ void gll16(const void* g, void* l) {
    __builtin_amdgcn_global_load_lds(
        (const __attribute__((address_space(1))) u32*)g,
        (__attribute__((address_space(3))) u32*)l, 16, 0, 0);
}

// stage 64 rows x 144 bf16 into LDS rows of stride 168 u16 (21 x 16B chunks).
// 192-thread (3-wave) version.
__device__ __forceinline__ void stage64(const u16* src, u32* lds, int tid) {
    const char* base = (const char*)src;
    char* lbase = (char*)lds;
    const int w = tid >> 6, l = tid & 63;
#pragma unroll
    for (int i = 0; i < 7; ++i) {
        int inst  = w * 7 + i;
        int chunk = inst * 64 + l;
        int row = chunk / 21;
        int col = chunk - row * 21;
        if (col > 17) col = 17;
        gll16(base + row * 288 + col * 16, lbase + inst * 1024);
    }
}

// 256-thread (4-wave) version: insts 0..20 over waves (6,6,6,3).
__device__ __forceinline__ void stage64_w4(const u16* src, u32* lds, int tid) {
    const char* base = (const char*)src;
    char* lbase = (char*)lds;
    const int w = tid >> 6, l = tid & 63;
#pragma unroll
    for (int i = 0; i < 6; ++i) {
        int inst = w * 6 + i;
        if (inst < 21) {
            int chunk = inst * 64 + l;
            int row = chunk / 21;
            int col = chunk - row * 21;
            if (col > 17) col = 17;
            gll16(base + row * 288 + col * 16, lbase + inst * 1024);
        }
    }
}

// ---------------- weight pack: f32 [rows x sstr] -> bf16 MFMA-fragment order ----
__global__ void wpack_kernel(const float* __restrict__ src, u16* __restrict__ dst,
                             int ntiles, int NS, int K, int sstr)
{
    int i = blockIdx.x * 256 + threadIdx.x;
    if (i >= ntiles * NS * 512) return;
    int e  = i & 7;
    int l  = (i >> 3) & 63;
    int c  = i >> 9;
    int s  = c % NS;
    int tile = c / NS;
    int li = l & 15, lg = l >> 4;
    int row = tile * 16 + li;
    int k   = s * 32 + lg * 8 + e;
    dst[i] = (k < K) ? f2bf(src[(size_t)row * sstr + k]) : (u16)0;
}

__global__ void cast_bf_kernel(const float* __restrict__ src, u16* __restrict__ dst,
                               int n2)
{
    int i = blockIdx.x * 256 + threadIdx.x;
    if (i >= n2) return;
    float2 t = ((const float2*)src)[i];
    ((u32*)dst)[i] = ((u32)f2bf(t.y) << 16) | (u32)f2bf(t.x);
}

// ---------------- qkv GEMM: full N=432 in one block (4 waves) -------------------
// Wave w owns weight tiles {w, w+4, ...}: 7 tiles (wave 3: 6). X staged once.
__global__ __launch_bounds__(256) void gemm_qkv(
    const u16* __restrict__ A, const u16* __restrict__ Wb,
    const float* __restrict__ bias, u16* __restrict__ C, int M)
{
    __shared__ u32 lds[64 * 84];

    const int tid = threadIdx.x;
    const int w   = tid >> 6;
    const int l   = tid & 63;
    const int lg  = l >> 4;
    const int li  = l & 15;
    const int bm  = blockIdx.x * 64;

    f32x4 acc[7][4];
#pragma unroll
    for (int ci = 0; ci < 7; ++ci)
#pragma unroll
        for (int rt = 0; rt < 4; ++rt) acc[ci][rt] = {0.f, 0.f, 0.f, 0.f};

    stage64_w4(A + (size_t)bm * 144, lds, tid);
    __syncthreads();

    const u16* lds16 = (const u16*)lds;
#pragma unroll
    for (int s = 0; s < 5; ++s) {
        short8v af[4];
#pragma unroll
        for (int rt = 0; rt < 4; ++rt)
            af[rt] = *(const short8v*)(lds16 + (rt * 16 + li) * 168 + s * 32 + lg * 8);
#pragma unroll
        for (int ci = 0; ci < 7; ++ci) {
            int ct = w + 4 * ci;
            if (ct < 27) {
                short8v bf = wfrag(Wb, ct, 5, s, l);
#pragma unroll
                for (int rt = 0; rt < 4; ++rt)
                    acc[ci][rt] = __builtin_amdgcn_mfma_f32_16x16x32_bf16(
                        af[rt], bf, acc[ci][rt], 0, 0, 0);
            }
        }
    }

#pragma unroll
    for (int ci = 0; ci < 7; ++ci) {
        int ct = w + 4 * ci;
        if (ct < 27) {
            int col = ct * 16 + li;
            float bv = bias[col];
#pragma unroll
            for (int rt = 0; rt < 4; ++rt)
#pragma unroll
                for (int j = 0; j < 4; ++j) {
                    int row = bm + rt * 16 + lg * 4 + j;
                    C[(size_t)row * TH_ + col] = f2bf(acc[ci][rt][j] + bv);
                }
        }
    }
}

// ======== fused: out-proj + res + LN1 + FFN + res + LN2 (column-split) ==========
template<bool RESBF, bool WF32>
__global__ __launch_bounds__(192) void olnffn_kernel(
    const u16* __restrict__ ob, const u16* __restrict__ Wo,
    const float* __restrict__ ob_b,
    const float* __restrict__ resf, const u16* __restrict__ resb,
    const float* __restrict__ ln1w, const float* __restrict__ ln1b,
    const u16* __restrict__ W1, const float* __restrict__ b1,
    const u16* __restrict__ W2, const float* __restrict__ b2,
    const float* __restrict__ ln2w, const float* __restrict__ ln2b,
    u16* __restrict__ obf, float* __restrict__ of)
{
    __shared__ __align__(16) u16 Als[64 * 168];
    __shared__ u32 Fls[64 * 52];
    __shared__ float lnS[3][64], lnQ[3][64];

    const int tid = threadIdx.x;
    const int w   = tid >> 6;
    const int l   = tid & 63;
    const int lg  = l >> 4;
    const int li  = l & 15;
    const int bm  = blockIdx.x * 64;

    stage64(ob + (size_t)bm * 144, (u32*)Als, tid);

    float rr[4][3][4];
#pragma unroll
    for (int ct = 0; ct < 3; ++ct) {
        int col = w * 48 + ct * 16 + li;
#pragma unroll
        for (int rt = 0; rt < 4; ++rt)
#pragma unroll
            for (int j = 0; j < 4; ++j) {
                int row = bm + rt * 16 + lg * 4 + j;
                rr[rt][ct][j] = RESBF ? bf2f(resb[(size_t)row * E_ + col])
                                      : resf[(size_t)row * E_ + col];
            }
    }
    __syncthreads();

    const u16* als = Als;
    u16* alsw = Als;
    u16* fls16 = (u16*)Fls;

    f32x4 acc[4][3];
#pragma unroll
    for (int rt = 0; rt < 4; rt++)
#pragma unroll
        for (int ct = 0; ct < 3; ct++) acc[rt][ct] = {0.f, 0.f, 0.f, 0.f};
#pragma unroll
    for (int s = 0; s < 5; ++s) {
        short8v bf[3];
#pragma unroll
        for (int ct = 0; ct < 3; ++ct)
            bf[ct] = wfrag(Wo, w * 3 + ct, 5, s, l);
        short8v af[4];
#pragma unroll
        for (int rt = 0; rt < 4; ++rt)
            af[rt] = *(const short8v*)(als + (rt * 16 + li) * 168 + s * 32 + lg * 8);
#pragma unroll
        for (int rt = 0; rt < 4; ++rt)
#pragma unroll
            for (int ct = 0; ct < 3; ++ct)
                acc[rt][ct] = __builtin_amdgcn_mfma_f32_16x16x32_bf16(
                    af[rt], bf[ct], acc[rt][ct], 0, 0, 0);
    }

    float vv[4][3][4];
#pragma unroll
    for (int ct = 0; ct < 3; ++ct) {
        int col = w * 48 + ct * 16 + li;
        float bv = ob_b[col];
#pragma unroll
        for (int rt = 0; rt < 4; ++rt)
#pragma unroll
            for (int j = 0; j < 4; ++j)
                vv[rt][ct][j] = acc[rt][ct][j] + bv + rr[rt][ct][j];
    }
#pragma unroll
    for (int rt = 0; rt < 4; ++rt)
#pragma unroll
        for (int j = 0; j < 4; ++j) {
            float s = vv[rt][0][j] + vv[rt][1][j] + vv[rt][2][j];
            float q = vv[rt][0][j] * vv[rt][0][j] + vv[rt][1][j] * vv[rt][1][j]
                    + vv[rt][2][j] * vv[rt][2][j];
#pragma unroll
            for (int off = 1; off < 16; off <<= 1) {
                s += __shfl_xor(s, off);
                q += __shfl_xor(q, off);
            }
            if (li == 0) {
                lnS[w][rt * 16 + lg * 4 + j] = s;
                lnQ[w][rt * 16 + lg * 4 + j] = q;
            }
        }
    __syncthreads();
#pragma unroll
    for (int rt = 0; rt < 4; ++rt)
#pragma unroll
        for (int j = 0; j < 4; ++j) {
            int r = rt * 16 + lg * 4 + j;
            float mean = (lnS[0][r] + lnS[1][r] + lnS[2][r]) * (1.f / 144.f);
            float var  = (lnQ[0][r] + lnQ[1][r] + lnQ[2][r]) * (1.f / 144.f) - mean * mean;
            float rstd = rsqrtf(var + 1e-5f);
#pragma unroll
            for (int ct = 0; ct < 3; ++ct) {
                int col = w * 48 + ct * 16 + li;
                float o = (vv[rt][ct][j] - mean) * rstd * ln1w[col] + ln1b[col];
                vv[rt][ct][j] = o;
                alsw[r * 168 + col] = f2bf(o);
            }
        }
    __syncthreads();

    f32x4 acc2[4][3];
#pragma unroll
    for (int rt = 0; rt < 4; rt++)
#pragma unroll
        for (int ct = 0; ct < 3; ct++) acc2[rt][ct] = {0.f, 0.f, 0.f, 0.f};

    for (int c = 0; c < 6; ++c) {
        f32x4 acc1[4][2];
#pragma unroll
        for (int rt = 0; rt < 4; rt++)
#pragma unroll
            for (int ct = 0; ct < 2; ct++) acc1[rt][ct] = {0.f, 0.f, 0.f, 0.f};
#pragma unroll
        for (int s = 0; s < 5; ++s) {
            short8v bf[2];
#pragma unroll
            for (int ct = 0; ct < 2; ++ct)
                bf[ct] = wfrag(W1, c * 6 + w * 2 + ct, 5, s, l);
            short8v af[4];
#pragma unroll
            for (int rt = 0; rt < 4; ++rt)
                af[rt] = *(const short8v*)(als + (rt * 16 + li) * 168 + s * 32 + lg * 8);
#pragma unroll
            for (int rt = 0; rt < 4; ++rt)
#pragma unroll
                for (int ct = 0; ct < 2; ++ct)
                    acc1[rt][ct] = __builtin_amdgcn_mfma_f32_16x16x32_bf16(
                        af[rt], bf[ct], acc1[rt][ct], 0, 0, 0);
        }
        __syncthreads();
#pragma unroll
        for (int ct = 0; ct < 2; ++ct) {
            int colc = w * 32 + ct * 16 + li;
            float bv = b1[c * 96 + colc];
#pragma unroll
            for (int rt = 0; rt < 4; ++rt)
#pragma unroll
                for (int j = 0; j < 4; ++j) {
                    int row = rt * 16 + lg * 4 + j;
                    float v = fmaxf(acc1[rt][ct][j] + bv, 0.f);
                    fls16[row * 104 + colc] = f2bf(v);
                }
        }
        __syncthreads();
#pragma unroll
        for (int s2 = 0; s2 < 3; ++s2) {
            short8v wf[3];
#pragma unroll
            for (int ct = 0; ct < 3; ++ct)
                wf[ct] = wfrag(W2, w * 3 + ct, 18, c * 3 + s2, l);
            short8v pf[4];
#pragma unroll
            for (int rt = 0; rt < 4; ++rt)
                pf[rt] = *(const short8v*)(fls16 + (rt * 16 + li) * 104 + s2 * 32 + lg * 8);
#pragma unroll
            for (int rt = 0; rt < 4; ++rt)
#pragma unroll
                for (int ct = 0; ct < 3; ++ct)
                    acc2[rt][ct] = __builtin_amdgcn_mfma_f32_16x16x32_bf16(
                        pf[rt], wf[ct], acc2[rt][ct], 0, 0, 0);
        }
    }

    float v2[4][3][4];
#pragma unroll
    for (int ct = 0; ct < 3; ++ct) {
        int col = w * 48 + ct * 16 + li;
        float bv = b2[col];
#pragma unroll
        for (int rt = 0; rt < 4; ++rt)
#pragma unroll
            for (int j = 0; j < 4; ++j)
                v2[rt][ct][j] = acc2[rt][ct][j] + bv + vv[rt][ct][j];
    }
#pragma unroll
    for (int rt = 0; rt < 4; ++rt)
#pragma unroll
        for (int j = 0; j < 4; ++j) {
            float s = v2[rt][0][j] + v2[rt][1][j] + v2[rt][2][j];
            float q = v2[rt][0][j] * v2[rt][0][j] + v2[rt][1][j] * v2[rt][1][j]
                    + v2[rt][2][j] * v2[rt][2][j];
#pragma unroll
            for (int off = 1; off < 16; off <<= 1) {
                s += __shfl_xor(s, off);
                q += __shfl_xor(q, off);
            }
            if (li == 0) {
                lnS[w][rt * 16 + lg * 4 + j] = s;
                lnQ[w][rt * 16 + lg * 4 + j] = q;
            }
        }
    __syncthreads();
#pragma unroll
    for (int rt = 0; rt < 4; ++rt)
#pragma unroll
        for (int j = 0; j < 4; ++j) {
            int r = rt * 16 + lg * 4 + j;
            float mean = (lnS[0][r] + lnS[1][r] + lnS[2][r]) * (1.f / 144.f);
            float var  = (lnQ[0][r] + lnQ[1][r] + lnQ[2][r]) * (1.f / 144.f) - mean * mean;
            float rstd = rsqrtf(var + 1e-5f);
            int row = bm + r;
#pragma unroll
            for (int ct = 0; ct < 3; ++ct) {
                int col = w * 48 + ct * 16 + li;
                float o = (v2[rt][ct][j] - mean) * rstd * ln2w[col] + ln2b[col];
                obf[(size_t)row * E_ + col] = f2bf(o);
                if (WF32) of[(size_t)row * E_ + col] = o;
            }
        }
}

// ---------------- f32 GEMM (small, ctx path) ------------------------------------
template<typename AT, typename OT, bool BIAS, bool RELU, bool RES>
__global__ __launch_bounds__(256) void gemm_kernel(
    const AT* __restrict__ A, const float* __restrict__ W, int ldw,
    const float* __restrict__ bias, const float* __restrict__ res,
    OT* __restrict__ C, int M, int N, int K)
{
    constexpr int BM = 64, BN = 64, BK = 16;
    __shared__ float As[BK][BM + 4];
    __shared__ float Ws[BK][BN + 4];
    const int tid = threadIdx.x;
    const int bm = blockIdx.y * BM;
    const int bn = blockIdx.x * BN;
    const int tx = tid & 15, ty = tid >> 4;
    const int lr = tid >> 2;
    const int lc = (tid & 3) << 2;

    float acc[4][4];
#pragma unroll
    for (int i = 0; i < 4; i++)
#pragma unroll
        for (int j = 0; j < 4; j++) acc[i][j] = 0.f;

    for (int k0 = 0; k0 < K; k0 += BK) {
        F4 av = load4(A + (size_t)(bm + lr) * K + k0 + lc);
        As[lc + 0][lr] = av.x; As[lc + 1][lr] = av.y;
        As[lc + 2][lr] = av.z; As[lc + 3][lr] = av.w;
        int n = bn + lr;
        F4 wv = {0.f, 0.f, 0.f, 0.f};
        if (n < N) {
            float4 t = *(const float4*)(W + (size_t)n * ldw + k0 + lc);
            wv = {t.x, t.y, t.z, t.w};
        }
        Ws[lc + 0][lr] = wv.x; Ws[lc + 1][lr] = wv.y;
        Ws[lc + 2][lr] = wv.z; Ws[lc + 3][lr] = wv.w;
        __syncthreads();
#pragma unroll
        for (int kk = 0; kk < BK; ++kk) {
            float a[4], wr[4];
#pragma unroll
            for (int i = 0; i < 4; i++) a[i] = As[kk][ty * 4 + i];
#pragma unroll
            for (int j = 0; j < 4; j++) wr[j] = Ws[kk][tx * 4 + j];
#pragma unroll
            for (int i = 0; i < 4; i++)
#pragma unroll
                for (int j = 0; j < 4; j++) acc[i][j] += a[i] * wr[j];
        }
        __syncthreads();
    }
#pragma unroll
    for (int i = 0; i < 4; i++) {
        int m = bm + ty * 4 + i;
#pragma unroll
        for (int j = 0; j < 4; j++) {
            int n = bn + tx * 4 + j;
            if (n < N) {
                float v = acc[i][j];
                if (BIAS) v += bias[n];
                if (RES)  v += res[(size_t)m * N + n];
                if (RELU) v = fmaxf(v, 0.f);
                store1(&C[(size_t)m * N + n], v);
            }
        }
    }
}

// ---------------- MFMA attention: one block (4 waves) per (b, head) -------------
__global__ __launch_bounds__(256) void attn_kernel(const u16* __restrict__ qkv,
                                                   u16* __restrict__ o)
{
    constexpr int QS = 40;
    constexpr int VS = 136;
    __shared__ __align__(16) u16 Qs[128 * QS];
    __shared__ __align__(16) u16 Ks[128 * QS];
    __shared__ __align__(16) u16 Vt[32 * VS];
    __shared__ __align__(16) u16 Ps[4][16 * VS];

    const int bh = blockIdx.x;
    const int b = bh >> 3, h = bh & 7;
    const int tid = threadIdx.x;
    const int w = tid >> 6, l = tid & 63;
    const int lg = l >> 4, li = l & 15;

    {
        u32* z1 = (u32*)Qs;
        for (int i = tid; i < 128 * QS / 2; i += 256) z1[i] = 0;
        u32* z2 = (u32*)Ks;
        for (int i = tid; i < 128 * QS / 2; i += 256) z2[i] = 0;
        u32* z3 = (u32*)Vt;
        for (int i = tid; i < 32 * VS / 2; i += 256) z3[i] = 0;
    }
    __syncthreads();

    const u32* q32 = (const u32*)(qkv + (size_t)b * T_ * TH_);
    for (int idx = tid; idx < 120 * 9; idx += 256) {
        int t = idx / 9, dp = idx - t * 9;
        u32 qv = q32[t * 216 + 9 * h + dp];
        u32 kv = q32[t * 216 + 72 + 9 * h + dp];
        u32 vv = q32[t * 216 + 144 + 9 * h + dp];
        ((u32*)(Qs + t * QS))[dp] = qv;
        ((u32*)(Ks + t * QS))[dp] = kv;
        Vt[(2 * dp) * VS + t]     = (u16)(vv & 0xffffu);
        Vt[(2 * dp + 1) * VS + t] = (u16)(vv >> 16);
    }
    __syncthreads();

    const float scale = 0.23570226039551584f;
    u16* pw = &Ps[w][0];

    for (int mt = w * 2; mt < w * 2 + 2; ++mt) {
        short8v qf = *(const short8v*)(Qs + (mt * 16 + li) * QS + lg * 8);
        f32x4 sacc[8];
#pragma unroll
        for (int nt = 0; nt < 8; ++nt) sacc[nt] = {0.f, 0.f, 0.f, 0.f};
#pragma unroll
        for (int nt = 0; nt < 8; ++nt) {
            short8v kf = *(const short8v*)(Ks + (nt * 16 + li) * QS + lg * 8);
            sacc[nt] = __builtin_amdgcn_mfma_f32_16x16x32_bf16(qf, kf, sacc[nt], 0, 0, 0);
        }

        float invl[4];
#pragma unroll
        for (int j = 0; j < 4; ++j) {
            float v[8];
            float m = -1e30f;
#pragma unroll
            for (int nt = 0; nt < 8; ++nt) {
                float s = sacc[nt][j] * scale;
                if (nt == 7 && li >= 8) s = -1e30f;
                v[nt] = s;
                m = fmaxf(m, s);
            }
#pragma unroll
            for (int off = 1; off < 16; off <<= 1)
                m = fmaxf(m, __shfl_xor(m, off));
            float sum = 0.f;
#pragma unroll
            for (int nt = 0; nt < 8; ++nt) {
                float p = __expf(v[nt] - m);
                sum += p;
                pw[(lg * 4 + j) * VS + nt * 16 + li] = f2bf(p);
            }
#pragma unroll
            for (int off = 1; off < 16; off <<= 1)
                sum += __shfl_xor(sum, off);
            invl[j] = 1.f / sum;
        }

        f32x4 oacc[2] = {{0.f,0.f,0.f,0.f},{0.f,0.f,0.f,0.f}};
#pragma unroll
        for (int s = 0; s < 4; ++s) {
            short8v pf = *(const short8v*)(pw + li * VS + s * 32 + lg * 8);
#pragma unroll
            for (int dt = 0; dt < 2; ++dt) {
                short8v vf = *(const short8v*)(Vt + (dt * 16 + li) * VS + s * 32 + lg * 8);
                oacc[dt] = __builtin_amdgcn_mfma_f32_16x16x32_bf16(pf, vf, oacc[dt], 0, 0, 0);
            }
        }

        const int q0 = mt * 16 + lg * 4;
#pragma unroll
        for (int dt = 0; dt < 2; ++dt) {
            int d = dt * 16 + li;
            if (d < HD_) {
#pragma unroll
                for (int j = 0; j < 4; ++j) {
                    int q = q0 + j;
                    if (q < T_)
                        o[((size_t)b * T_ + q) * E_ + h * HD_ + d] =
                            f2bf(oacc[dt][j] * invl[j]);
                }
            }
        }
    }
}

// ---------------- mean over T ----------------------------------------------------
__global__ void mean_kernel(const float* __restrict__ x, float* __restrict__ out,
                            int nb)
{
    int idx = blockIdx.x * blockDim.x + threadIdx.x;
    if (idx >= nb * E_) return;
    int b = idx / E_, e = idx % E_;
    const float* p = x + (size_t)b * T_ * E_ + e;
    float s = 0.f;
    for (int t = 0; t < T_; t++) s += p[(size_t)t * E_];
    out[idx] = s * (1.f / 120.f);
}

__device__ __forceinline__ float sigmoidf_(float x) {
    return 1.f / (1.f + __expf(-x));
}

// ======== persistent GRU decode: 8 rows/block -> 256 blocks (full CU coverage) ==
#define GRU_M 8
__global__ __launch_bounds__(192) void gru_all_kernel(
    const float* __restrict__ seed,
    const float* __restrict__ gctx,
    const u16* __restrict__ WxB,
    const u16* __restrict__ WhB,
    const u16* __restrict__ SpB,
    const float* __restrict__ b_hh,
    const float* __restrict__ spl_b,
    float* __restrict__ out)
{
    __shared__ __align__(16) u16 xls[16 * 168];   // 16 rows (8 real + 8 zero)
    __shared__ __align__(16) u16 hls[16 * 168];

    const int tid = threadIdx.x;
    const int w = tid >> 6, l = tid & 63;
    const int lg = l >> 4, li = l & 15;
    const int b0 = blockIdx.x * GRU_M;
    const int fr = w * 48 + li;
    const bool rowok = (lg < 2);          // rows lg*4+j < 8

    for (int i = tid; i < 16 * 84; i += 192) {
        ((u32*)xls)[i] = 0; ((u32*)hls)[i] = 0;
    }
    __syncthreads();
    for (int i = tid; i < GRU_M * 72; i += 192) {
        int r = i / 72, e2 = i - r * 72;
        float2 t = *(const float2*)(seed + (size_t)(b0 + r) * T_ * E_
                                    + (size_t)(T_ - 1) * E_ + 2 * e2);
        ((u32*)(xls + r * 168))[e2] = ((u32)f2bf(t.y) << 16) | (u32)f2bf(t.x);
    }

    float gctxv[3][3][4];
    float bhh[3][3];
    float splb[3];
#pragma unroll
    for (int g = 0; g < 3; ++g)
#pragma unroll
        for (int ct = 0; ct < 3; ++ct) {
            int f = g * 144 + fr + ct * 16;
            bhh[g][ct] = b_hh[f];
#pragma unroll
            for (int j = 0; j < 4; ++j) {
                int rb = b0 + lg * 4 + j;
                if (rb >= B_) rb = B_ - 1;     // clamp (fake rows only)
                gctxv[g][ct][j] = gctx[(size_t)rb * TH_ + f];
            }
        }
#pragma unroll
    for (int ct = 0; ct < 3; ++ct) splb[ct] = spl_b[fr + ct * 16];

    float hold[3][4];
#pragma unroll
    for (int ct = 0; ct < 3; ++ct)
#pragma unroll
        for (int j = 0; j < 4; ++j) hold[ct][j] = 0.f;

    __syncthreads();

    for (int st = 0; st < FUT_; ++st) {
        f32x4 aRZ[2][3], aNi[3], aNh[3];
#pragma unroll
        for (int g = 0; g < 2; ++g)
#pragma unroll
            for (int ct = 0; ct < 3; ++ct) aRZ[g][ct] = {0.f, 0.f, 0.f, 0.f};
#pragma unroll
        for (int ct = 0; ct < 3; ++ct) {
            aNi[ct] = {0.f, 0.f, 0.f, 0.f};
            aNh[ct] = {0.f, 0.f, 0.f, 0.f};
        }
#pragma unroll
        for (int s = 0; s < 5; ++s) {
            short8v ax = *(const short8v*)(xls + li * 168 + s * 32 + lg * 8);
            short8v ah = *(const short8v*)(hls + li * 168 + s * 32 + lg * 8);
#pragma unroll
            for (int ct = 0; ct < 3; ++ct) {
#pragma unroll
                for (int g = 0; g < 2; ++g) {
                    int tile = g * 9 + w * 3 + ct;
                    short8v bx = wfrag(WxB, tile, 5, s, l);
                    aRZ[g][ct] = __builtin_amdgcn_mfma_f32_16x16x32_bf16(ax, bx, aRZ[g][ct], 0, 0, 0);
                    short8v bh = wfrag(WhB, tile, 5, s, l);
                    aRZ[g][ct] = __builtin_amdgcn_mfma_f32_16x16x32_bf16(ah, bh, aRZ[g][ct], 0, 0, 0);
                }
                int tile2 = 18 + w * 3 + ct;
                short8v bx2 = wfrag(WxB, tile2, 5, s, l);
                aNi[ct] = __builtin_amdgcn_mfma_f32_16x16x32_bf16(ax, bx2, aNi[ct], 0, 0, 0);
                short8v bh2 = wfrag(WhB, tile2, 5, s, l);
                aNh[ct] = __builtin_amdgcn_mfma_f32_16x16x32_bf16(ah, bh2, aNh[ct], 0, 0, 0);
            }
        }
        __syncthreads();
#pragma unroll
        for (int ct = 0; ct < 3; ++ct)
#pragma unroll
            for (int j = 0; j < 4; ++j) {
                float r = sigmoidf_(aRZ[0][ct][j] + gctxv[0][ct][j] + bhh[0][ct]);
                float z = sigmoidf_(aRZ[1][ct][j] + gctxv[1][ct][j] + bhh[1][ct]);
                float n = tanhf(aNi[ct][j] + gctxv[2][ct][j]
                                + r * (aNh[ct][j] + bhh[2][ct]));
                float hv = (1.f - z) * n + z * hold[ct][j];
                hold[ct][j] = hv;
                if (rowok)
                    hls[(lg * 4 + j) * 168 + fr + ct * 16] = f2bf(hv);
            }
        __syncthreads();
        f32x4 aS[3];
#pragma unroll
        for (int ct = 0; ct < 3; ++ct) aS[ct] = {0.f, 0.f, 0.f, 0.f};
#pragma unroll
        for (int s = 0; s < 5; ++s) {
            short8v ah = *(const short8v*)(hls + li * 168 + s * 32 + lg * 8);
#pragma unroll
            for (int ct = 0; ct < 3; ++ct) {
                short8v bs = wfrag(SpB, w * 3 + ct, 5, s, l);
                aS[ct] = __builtin_amdgcn_mfma_f32_16x16x32_bf16(ah, bs, aS[ct], 0, 0, 0);
            }
        }
#pragma unroll
        for (int ct = 0; ct < 3; ++ct) {
            int col = fr + ct * 16;
#pragma unroll
            for (int j = 0; j < 4; ++j) {
                if (rowok) {
                    float rv = aS[ct][j] + splb[ct];
                    out[(size_t)(b0 + lg * 4 + j) * (FUT_ * E_) + (size_t)st * E_ + col] = rv;
                    xls[(lg * 4 + j) * 168 + col] = f2bf(rv);
                }
            }
        }
        __syncthreads();
    }
}

// =================================================================================
extern "C" void kernel_launch(void* const* d_in, const int* in_sizes, int n_in,
                              void* d_out, int out_size, void* d_ws, size_t ws_size,
                              hipStream_t stream)
{
    const float* seed   = (const float*)d_in[0];
    const float* qkv_w  = (const float*)d_in[1];
    const float* qkv_b  = (const float*)d_in[2];
    const float* out_w  = (const float*)d_in[3];
    const float* out_b  = (const float*)d_in[4];
    const float* ln1_w  = (const float*)d_in[5];
    const float* ln1_b  = (const float*)d_in[6];
    const float* ffn1_w = (const float*)d_in[7];
    const float* ffn1_b = (const float*)d_in[8];
    const float* ffn2_w = (const float*)d_in[9];
    const float* ffn2_b = (const float*)d_in[10];
    const float* ln2_w  = (const float*)d_in[11];
    const float* ln2_b  = (const float*)d_in[12];
    const float* proj_w = (const float*)d_in[13];
    const float* proj_b = (const float*)d_in[14];
    const float* w_ih   = (const float*)d_in[15];
    const float* w_hh   = (const float*)d_in[16];
    const float* b_ih   = (const float*)d_in[17];
    const float* b_hh   = (const float*)d_in[18];
    const float* spl_w  = (const float*)d_in[19];
    const float* spl_b  = (const float*)d_in[20];

    const size_t qkvW_n  = (size_t)L_ * TH_ * 160;
    const size_t outW_n  = (size_t)L_ * E_ * 160;
    const size_t ffn1W_n = (size_t)L_ * FF_ * 160;
    const size_t ffn2W_n = (size_t)L_ * E_ * 576;
    const size_t wxW_n   = (size_t)TH_ * 160;
    const size_t whW_n   = (size_t)TH_ * 160;
    const size_t spW_n   = (size_t)E_ * 160;
    const size_t wbytes  = (qkvW_n + outW_n + ffn1W_n + ffn2W_n
                            + wxW_n + whW_n + spW_n) * 2;

    const size_t persist = (size_t)B_ * 4 * (E_ + E_ + TH_) + wbytes;

    int nc = 16;
    for (int c = 1; c <= 16; c <<= 1) {
        size_t rows = (size_t)(B_ / c) * T_;
        size_t need = persist + rows * 2016;
        if (need <= ws_size) { nc = c; break; }
    }
    const int BC = B_ / nc;
    const int CR = BC * T_;

    char* wsp = (char*)d_ws;
    u16*   xbf   = (u16*)wsp;   wsp += (size_t)CR * E_ * 2;
    float* xres  = (float*)wsp; wsp += (size_t)CR * E_ * 4;
    u16*   qf    = (u16*)wsp;   wsp += (size_t)CR * TH_ * 2;
    u16*   ob    = (u16*)wsp;   wsp += (size_t)CR * E_ * 2;
    float* ctxm  = (float*)wsp; wsp += (size_t)B_ * E_ * 4;
    float* ctx   = (float*)wsp; wsp += (size_t)B_ * E_ * 4;
    float* gctx  = (float*)wsp; wsp += (size_t)B_ * TH_ * 4;
    u16* qkvWb   = (u16*)wsp;   wsp += qkvW_n * 2;
    u16* outWb   = (u16*)wsp;   wsp += outW_n * 2;
    u16* ffn1Wb  = (u16*)wsp;   wsp += ffn1W_n * 2;
    u16* ffn2Wb  = (u16*)wsp;   wsp += ffn2W_n * 2;
    u16* wxB     = (u16*)wsp;   wsp += wxW_n * 2;
    u16* whB     = (u16*)wsp;   wsp += whW_n * 2;
    u16* splWb   = (u16*)wsp;   wsp += spW_n * 2;

    wpack_kernel<<<(int)((qkvW_n + 255) / 256), 256, 0, stream>>>(qkv_w, qkvWb, L_ * 27, 5, 144, 144);
    wpack_kernel<<<(int)((outW_n + 255) / 256), 256, 0, stream>>>(out_w, outWb, L_ * 9, 5, 144, 144);
    wpack_kernel<<<(int)((ffn1W_n + 255) / 256), 256, 0, stream>>>(ffn1_w, ffn1Wb, L_ * 36, 5, 144, 144);
    wpack_kernel<<<(int)((ffn2W_n + 255) / 256), 256, 0, stream>>>(ffn2_w, ffn2Wb, L_ * 9, 18, 576, 576);
    wpack_kernel<<<(int)((wxW_n + 255) / 256), 256, 0, stream>>>(w_ih, wxB, 27, 5, 144, GIN_);
    wpack_kernel<<<(int)((whW_n + 255) / 256), 256, 0, stream>>>(w_hh, whB, 27, 5, 144, 144);
    wpack_kernel<<<(int)((spW_n + 255) / 256), 256, 0, stream>>>(spl_w, splWb, 9, 5, 144, 144);

    auto grid = [](int M, int N) { return dim3((N + 63) / 64, M / 64); };

    for (int c = 0; c < nc; c++) {
        const int b0 = c * BC;
        cast_bf_kernel<<<(CR * 72 + 255) / 256, 256, 0, stream>>>(
            seed + (size_t)b0 * T_ * E_, xbf, CR * 72);
        for (int l = 0; l < L_; l++) {
            gemm_qkv<<<CR / 64, 256, 0, stream>>>(
                xbf, qkvWb + (size_t)l * TH_ * 160, qkv_b + (size_t)l * TH_, qf, CR);
            attn_kernel<<<BC * NH_, 256, 0, stream>>>(qf, ob);
            if (l == 0) {
                olnffn_kernel<false, false><<<CR / 64, 192, 0, stream>>>(
                    ob, outWb + (size_t)l * E_ * 160, out_b + (size_t)l * E_,
                    seed + (size_t)b0 * T_ * E_, nullptr,
                    ln1_w + (size_t)l * E_, ln1_b + (size_t)l * E_,
                    ffn1Wb + (size_t)l * FF_ * 160, ffn1_b + (size_t)l * FF_,
                    ffn2Wb + (size_t)l * E_ * 576, ffn2_b + (size_t)l * E_,
                    ln2_w + (size_t)l * E_, ln2_b + (size_t)l * E_, xbf, nullptr);
            } else if (l < 3) {
                olnffn_kernel<true, false><<<CR / 64, 192, 0, stream>>>(
                    ob, outWb + (size_t)l * E_ * 160, out_b + (size_t)l * E_,
                    nullptr, xbf,
                    ln1_w + (size_t)l * E_, ln1_b + (size_t)l * E_,
                    ffn1Wb + (size_t)l * FF_ * 160, ffn1_b + (size_t)l * FF_,
                    ffn2Wb + (size_t)l * E_ * 576, ffn2_b + (size_t)l * E_,
                    ln2_w + (size_t)l * E_, ln2_b + (size_t)l * E_, xbf, nullptr);
            } else {
                olnffn_kernel<true, true><<<CR / 64, 192, 0, stream>>>(
                    ob, outWb + (size_t)l * E_ * 160, out_b + (size_t)l * E_,
                    nullptr, xbf,
                    ln1_w + (size_t)l * E_, ln1_b + (size_t)l * E_,
                    ffn1Wb + (size_t)l * FF_ * 160, ffn1_b + (size_t)l * FF_,
                    ffn2Wb + (size_t)l * E_ * 576, ffn2_b + (size_t)l * E_,
                    ln2_w + (size_t)l * E_, ln2_b + (size_t)l * E_, xbf, xres);
            }
        }
        mean_kernel<<<(BC * E_ + 255) / 256, 256, 0, stream>>>(xres, ctxm + (size_t)b0 * E_, BC);
    }

    gemm_kernel<float, float, true, false, false><<<grid(B_, E_), 256, 0, stream>>>(
        ctxm, proj_w, E_, proj_b, nullptr, ctx, B_, E_, E_);
    gemm_kernel<float, float, true, false, false><<<grid(B_, TH_), 256, 0, stream>>>(
        ctx, w_ih + E_, GIN_, b_ih, nullptr, gctx, B_, TH_, E_);

    gru_all_kernel<<<B_ / GRU_M, 192, 0, stream>>>(
        seed, gctx, wxB, whB, splWb, b_hh, spl_b, (float*)d_out);
}

// Round 15
// 2782.794 us; speedup vs baseline: 1.5139x; 1.0517x over previous
//
#include <hip/hip_runtime.h>

#define B_   2048
#define T_   120
#define E_   144
#define L_   4
#define NH_  8
#define HD_  18
#define FF_  576
#define H_   144
#define GIN_ 288
#define TH_  432   // 3*E = 3*H
#define FUT_ 24
#define BT_  (B_*T_)

typedef unsigned short u16;
typedef unsigned int   u32;

typedef __attribute__((ext_vector_type(8))) short short8v;  // 8 bf16 (4 VGPRs)
typedef __attribute__((ext_vector_type(4))) float f32x4;

__device__ __forceinline__ float bf2f(u16 u) {
    u32 x = ((u32)u) << 16;
    return __uint_as_float(x);
}
__device__ __forceinline__ u16 f2bf(float f) {
    u32 x = __float_as_uint(f);
    u32 r = (x + 0x7fffu + ((x >> 16) & 1u)) >> 16;
    return (u16)r;
}

struct F4 { float x, y, z, w; };

__device__ __forceinline__ F4 load4(const float* p) {
    float4 v = *(const float4*)p;
    return {v.x, v.y, v.z, v.w};
}
__device__ __forceinline__ void store1(float* p, float v) { *p = v; }
__device__ __forceinline__ void store1(u16* p, float v)   { *p = f2bf(v); }

// ---- async global->LDS, 16B per lane, wave-uniform LDS base ---------------------
__device__ __forceinline__ void gll16(const void* g, void* l) {
    __builtin_amdgcn_global_load_lds(
        (const __attribute__((address_space(1))) u32*)g,
        (__attribute__((address_space(3))) u32*)l, 16, 0, 0);
}

// stage 64 rows x 144 bf16 (contiguous, row stride 288B) into LDS rows of
// stride 168 u16 (=336B = 21 x 16B chunks). Chunk-linear in LDS. Pad chunks
// (col 18..20) duplicate chunk 17 (finite junk x zero weight-pad = 0).
__device__ __forceinline__ void stage64(const u16* src, u32* lds, int tid) {
    const char* base = (const char*)src;
    char* lbase = (char*)lds;
    const int w = tid >> 6, l = tid & 63;
#pragma unroll
    for (int i = 0; i < 7; ++i) {
        int inst  = w * 7 + i;            // 0..20
        int chunk = inst * 64 + l;        // 0..1343
        int row = chunk / 21;
        int col = chunk - row * 21;
        if (col > 17) col = 17;
        gll16(base + row * 288 + col * 16, lbase + inst * 1024);
    }
}

// ---------------- weight convert + K-pad to bf16 (src row stride sstr) ----------
__global__ void wconv_kernel(const float* __restrict__ src, u16* __restrict__ dst,
                             int rows, int K, int KP, int sstr)
{
    int i = blockIdx.x * 256 + threadIdx.x;
    if (i >= rows * KP) return;
    int r = i / KP, k = i - r * KP;
    dst[i] = (k < K) ? f2bf(src[(size_t)r * sstr + k]) : (u16)0;
}

// ---------------- f32 -> bf16 cast (paired) -------------------------------------
__global__ void cast_bf_kernel(const float* __restrict__ src, u16* __restrict__ dst,
                               int n2)
{
    int i = blockIdx.x * 256 + threadIdx.x;
    if (i >= n2) return;
    float2 t = ((const float2*)src)[i];
    ((u32*)dst)[i] = ((u32)f2bf(t.y) << 16) | (u32)f2bf(t.x);
}

// ---------------- MFMA GEMM: C[M,N] = A[M,K] @ Wb[N,160]^T (+bias) --------------
// 192 threads = 3 waves. Block tile 64 x 144. qkv projection (N=432).
template<typename OT>
__global__ __launch_bounds__(192) void gemm_mfma(
    const u16* __restrict__ A, const u16* __restrict__ Wb,
    const float* __restrict__ bias, OT* __restrict__ C, int M, int N)
{
    constexpr int RS32 = 84;
    __shared__ u32 lds[64 * RS32];

    const int tid = threadIdx.x;
    const int w   = tid >> 6;
    const int l   = tid & 63;
    const int lg  = l >> 4;
    const int li  = l & 15;
    const int bm  = blockIdx.y * 64;
    const int n0w = blockIdx.x * 144 + w * 48;

    f32x4 acc[4][3];
#pragma unroll
    for (int rt = 0; rt < 4; rt++)
#pragma unroll
        for (int ct = 0; ct < 3; ct++) acc[rt][ct] = {0.f, 0.f, 0.f, 0.f};

    stage64(A + (size_t)bm * 144, lds, tid);
    __syncthreads();

    const u16* lds16 = (const u16*)lds;
#pragma unroll
    for (int s = 0; s < 5; ++s) {
        short8v bf[3];
#pragma unroll
        for (int ct = 0; ct < 3; ++ct) {
            int n = n0w + ct * 16 + li;
            bf[ct] = *(const short8v*)(Wb + (size_t)n * 160 + s * 32 + lg * 8);
        }
        short8v af[4];
#pragma unroll
        for (int rt = 0; rt < 4; ++rt)
            af[rt] = *(const short8v*)(lds16 + (rt * 16 + li) * (2 * RS32) + s * 32 + lg * 8);
#pragma unroll
        for (int rt = 0; rt < 4; ++rt)
#pragma unroll
            for (int ct = 0; ct < 3; ++ct)
                acc[rt][ct] = __builtin_amdgcn_mfma_f32_16x16x32_bf16(
                    af[rt], bf[ct], acc[rt][ct], 0, 0, 0);
    }

#pragma unroll
    for (int ct = 0; ct < 3; ++ct) {
        int col = n0w + ct * 16 + li;
        float bv = bias[col];
#pragma unroll
        for (int rt = 0; rt < 4; ++rt) {
#pragma unroll
            for (int j = 0; j < 4; ++j) {
                int row = bm + rt * 16 + lg * 4 + j;
                store1(&C[(size_t)row * N + col], acc[rt][ct][j] + bv);
            }
        }
    }
}

// ======== fused: out-proj + bias + res + LN1 + FFN + res + LN2 -> bf16,f32 ======
// 192 thr (3 waves), 64 rows/block. ff in 6 chunks of 96 cols (low VGPR/LDS).
__global__ __launch_bounds__(192) void olnffn_kernel(
    const u16* __restrict__ ob, const u16* __restrict__ Wo,
    const float* __restrict__ ob_b, const float* __restrict__ res,
    const float* __restrict__ ln1w, const float* __restrict__ ln1b,
    const u16* __restrict__ W1, const float* __restrict__ b1,
    const u16* __restrict__ W2, const float* __restrict__ b2,
    const float* __restrict__ ln2w, const float* __restrict__ ln2b,
    u16* __restrict__ obf, float* __restrict__ of)
{
    constexpr int RSA = 84;    // A-buffer row stride (u32)
    constexpr int RSF = 52;    // ff 96-col chunk row stride (u32)
    __shared__ u32 Als[64 * RSA];   // 21504 B
    __shared__ u32 Fls[64 * RSF];   // 13312 B
    __shared__ float lnS[3][64], lnQ[3][64];  // 1536 B

    const int tid = threadIdx.x;
    const int w   = tid >> 6;
    const int l   = tid & 63;
    const int lg  = l >> 4;
    const int li  = l & 15;
    const int bm  = blockIdx.x * 64;

    stage64(ob + (size_t)bm * 144, Als, tid);
    __syncthreads();

    const u16* als16 = (const u16*)Als;
    u16* als16w = (u16*)Als;
    u16* fls16 = (u16*)Fls;

    // ---- out-proj MFMA ----
    f32x4 acc[4][3];
#pragma unroll
    for (int rt = 0; rt < 4; rt++)
#pragma unroll
        for (int ct = 0; ct < 3; ct++) acc[rt][ct] = {0.f, 0.f, 0.f, 0.f};
#pragma unroll
    for (int s = 0; s < 5; ++s) {
        short8v bf[3];
#pragma unroll
        for (int ct = 0; ct < 3; ++ct) {
            int n = w * 48 + ct * 16 + li;
            bf[ct] = *(const short8v*)(Wo + (size_t)n * 160 + s * 32 + lg * 8);
        }
        short8v af[4];
#pragma unroll
        for (int rt = 0; rt < 4; ++rt)
            af[rt] = *(const short8v*)(als16 + (rt * 16 + li) * (2 * RSA) + s * 32 + lg * 8);
#pragma unroll
        for (int rt = 0; rt < 4; ++rt)
#pragma unroll
            for (int ct = 0; ct < 3; ++ct)
                acc[rt][ct] = __builtin_amdgcn_mfma_f32_16x16x32_bf16(
                    af[rt], bf[ct], acc[rt][ct], 0, 0, 0);
    }

    // ---- + bias + residual ----
    float vv[4][3][4];
#pragma unroll
    for (int ct = 0; ct < 3; ++ct) {
        int col = w * 48 + ct * 16 + li;
        float bv = ob_b[col];
#pragma unroll
        for (int rt = 0; rt < 4; ++rt)
#pragma unroll
            for (int j = 0; j < 4; ++j) {
                int row = bm + rt * 16 + lg * 4 + j;
                vv[rt][ct][j] = acc[rt][ct][j] + bv + res[(size_t)row * E_ + col];
            }
    }
    // ---- LN1 cross-wave reduce ----
#pragma unroll
    for (int rt = 0; rt < 4; ++rt)
#pragma unroll
        for (int j = 0; j < 4; ++j) {
            float s = vv[rt][0][j] + vv[rt][1][j] + vv[rt][2][j];
            float q = vv[rt][0][j] * vv[rt][0][j] + vv[rt][1][j] * vv[rt][1][j]
                    + vv[rt][2][j] * vv[rt][2][j];
#pragma unroll
            for (int off = 1; off < 16; off <<= 1) {
                s += __shfl_xor(s, off);
                q += __shfl_xor(q, off);
            }
            if (li == 0) {
                lnS[w][rt * 16 + lg * 4 + j] = s;
                lnQ[w][rt * 16 + lg * 4 + j] = q;
            }
        }
    __syncthreads();   // also guarantees all Als reads (out-proj) retired
    // ---- LN1 apply: keep f32 in vv (= FFN residual), write bf16 into Als ----
#pragma unroll
    for (int rt = 0; rt < 4; ++rt)
#pragma unroll
        for (int j = 0; j < 4; ++j) {
            int r = rt * 16 + lg * 4 + j;
            float mean = (lnS[0][r] + lnS[1][r] + lnS[2][r]) * (1.f / 144.f);
            float var  = (lnQ[0][r] + lnQ[1][r] + lnQ[2][r]) * (1.f / 144.f) - mean * mean;
            float rstd = rsqrtf(var + 1e-5f);
#pragma unroll
            for (int ct = 0; ct < 3; ++ct) {
                int col = w * 48 + ct * 16 + li;
                float o = (vv[rt][ct][j] - mean) * rstd * ln1w[col] + ln1b[col];
                vv[rt][ct][j] = o;                       // res2, f32
                als16w[r * (2 * RSA) + col] = f2bf(o);   // ffn1 A (pads: junk*0)
            }
        }
    __syncthreads();

    // ---- FFN: 6 chunks of 96 ff-cols ----
    f32x4 acc2[4][3];
#pragma unroll
    for (int rt = 0; rt < 4; rt++)
#pragma unroll
        for (int ct = 0; ct < 3; ct++) acc2[rt][ct] = {0.f, 0.f, 0.f, 0.f};

    for (int c = 0; c < 6; ++c) {
        f32x4 acc1[4][2];
#pragma unroll
        for (int rt = 0; rt < 4; rt++)
#pragma unroll
            for (int ct = 0; ct < 2; ct++) acc1[rt][ct] = {0.f, 0.f, 0.f, 0.f};
#pragma unroll
        for (int s = 0; s < 5; ++s) {
            short8v bf[2];
#pragma unroll
            for (int ct = 0; ct < 2; ++ct) {
                int n1 = c * 96 + w * 32 + ct * 16 + li;
                bf[ct] = *(const short8v*)(W1 + (size_t)n1 * 160 + s * 32 + lg * 8);
            }
            short8v af[4];
#pragma unroll
            for (int rt = 0; rt < 4; ++rt)
                af[rt] = *(const short8v*)(als16 + (rt * 16 + li) * (2 * RSA) + s * 32 + lg * 8);
#pragma unroll
            for (int rt = 0; rt < 4; ++rt)
#pragma unroll
                for (int ct = 0; ct < 2; ++ct)
                    acc1[rt][ct] = __builtin_amdgcn_mfma_f32_16x16x32_bf16(
                        af[rt], bf[ct], acc1[rt][ct], 0, 0, 0);
        }
        __syncthreads();   // prev-chunk ffn2 reads of Fls complete
#pragma unroll
        for (int ct = 0; ct < 2; ++ct) {
            int colc = w * 32 + ct * 16 + li;
            float bv = b1[c * 96 + colc];
#pragma unroll
            for (int rt = 0; rt < 4; ++rt)
#pragma unroll
                for (int j = 0; j < 4; ++j) {
                    int row = rt * 16 + lg * 4 + j;
                    float v = fmaxf(acc1[rt][ct][j] + bv, 0.f);
                    fls16[row * (2 * RSF) + colc] = f2bf(v);
                }
        }
        __syncthreads();
#pragma unroll
        for (int s2 = 0; s2 < 3; ++s2) {
            short8v wf[3];
#pragma unroll
            for (int ct = 0; ct < 3; ++ct) {
                int n2 = w * 48 + ct * 16 + li;
                wf[ct] = *(const short8v*)(W2 + (size_t)n2 * 576 + c * 96 + s2 * 32 + lg * 8);
            }
            short8v pf[4];
#pragma unroll
            for (int rt = 0; rt < 4; ++rt)
                pf[rt] = *(const short8v*)(fls16 + (rt * 16 + li) * (2 * RSF) + s2 * 32 + lg * 8);
#pragma unroll
            for (int rt = 0; rt < 4; ++rt)
#pragma unroll
                for (int ct = 0; ct < 3; ++ct)
                    acc2[rt][ct] = __builtin_amdgcn_mfma_f32_16x16x32_bf16(
                        pf[rt], wf[ct], acc2[rt][ct], 0, 0, 0);
        }
    }

    // ---- epilogue: + b2 + res2(regs) -> LN2 -> write bf16 + f32 ----
    float v2[4][3][4];
#pragma unroll
    for (int ct = 0; ct < 3; ++ct) {
        int col = w * 48 + ct * 16 + li;
        float bv = b2[col];
#pragma unroll
        for (int rt = 0; rt < 4; ++rt)
#pragma unroll
            for (int j = 0; j < 4; ++j)
                v2[rt][ct][j] = acc2[rt][ct][j] + bv + vv[rt][ct][j];
    }
#pragma unroll
    for (int rt = 0; rt < 4; ++rt)
#pragma unroll
        for (int j = 0; j < 4; ++j) {
            float s = v2[rt][0][j] + v2[rt][1][j] + v2[rt][2][j];
            float q = v2[rt][0][j] * v2[rt][0][j] + v2[rt][1][j] * v2[rt][1][j]
                    + v2[rt][2][j] * v2[rt][2][j];
#pragma unroll
            for (int off = 1; off < 16; off <<= 1) {
                s += __shfl_xor(s, off);
                q += __shfl_xor(q, off);
            }
            if (li == 0) {
                lnS[w][rt * 16 + lg * 4 + j] = s;
                lnQ[w][rt * 16 + lg * 4 + j] = q;
            }
        }
    __syncthreads();
#pragma unroll
    for (int rt = 0; rt < 4; ++rt)
#pragma unroll
        for (int j = 0; j < 4; ++j) {
            int r = rt * 16 + lg * 4 + j;
            float mean = (lnS[0][r] + lnS[1][r] + lnS[2][r]) * (1.f / 144.f);
            float var  = (lnQ[0][r] + lnQ[1][r] + lnQ[2][r]) * (1.f / 144.f) - mean * mean;
            float rstd = rsqrtf(var + 1e-5f);
            int row = bm + r;
#pragma unroll
            for (int ct = 0; ct < 3; ++ct) {
                int col = w * 48 + ct * 16 + li;
                float o = (v2[rt][ct][j] - mean) * rstd * ln2w[col] + ln2b[col];
                obf[(size_t)row * E_ + col] = f2bf(o);
                of[(size_t)row * E_ + col]  = o;
            }
        }
}

// ---------------- f32 GEMM (small, ctx path): C = A @ W^T + bias ----------------
template<typename AT, typename OT, bool BIAS, bool RELU, bool RES>
__global__ __launch_bounds__(256) void gemm_kernel(
    const AT* __restrict__ A, const float* __restrict__ W, int ldw,
    const float* __restrict__ bias, const float* __restrict__ res,
    OT* __restrict__ C, int M, int N, int K)
{
    constexpr int BM = 64, BN = 64, BK = 16;
    __shared__ float As[BK][BM + 4];
    __shared__ float Ws[BK][BN + 4];
    const int tid = threadIdx.x;
    const int bm = blockIdx.y * BM;
    const int bn = blockIdx.x * BN;
    const int tx = tid & 15, ty = tid >> 4;
    const int lr = tid >> 2;
    const int lc = (tid & 3) << 2;

    float acc[4][4];
#pragma unroll
    for (int i = 0; i < 4; i++)
#pragma unroll
        for (int j = 0; j < 4; j++) acc[i][j] = 0.f;

    for (int k0 = 0; k0 < K; k0 += BK) {
        F4 av = load4(A + (size_t)(bm + lr) * K + k0 + lc);
        As[lc + 0][lr] = av.x; As[lc + 1][lr] = av.y;
        As[lc + 2][lr] = av.z; As[lc + 3][lr] = av.w;
        int n = bn + lr;
        F4 wv = {0.f, 0.f, 0.f, 0.f};
        if (n < N) {
            float4 t = *(const float4*)(W + (size_t)n * ldw + k0 + lc);
            wv = {t.x, t.y, t.z, t.w};
        }
        Ws[lc + 0][lr] = wv.x; Ws[lc + 1][lr] = wv.y;
        Ws[lc + 2][lr] = wv.z; Ws[lc + 3][lr] = wv.w;
        __syncthreads();
#pragma unroll
        for (int kk = 0; kk < BK; ++kk) {
            float a[4], wr[4];
#pragma unroll
            for (int i = 0; i < 4; i++) a[i] = As[kk][ty * 4 + i];
#pragma unroll
            for (int j = 0; j < 4; j++) wr[j] = Ws[kk][tx * 4 + j];
#pragma unroll
            for (int i = 0; i < 4; i++)
#pragma unroll
                for (int j = 0; j < 4; j++) acc[i][j] += a[i] * wr[j];
        }
        __syncthreads();
    }
#pragma unroll
    for (int i = 0; i < 4; i++) {
        int m = bm + ty * 4 + i;
#pragma unroll
        for (int j = 0; j < 4; j++) {
            int n = bn + tx * 4 + j;
            if (n < N) {
                float v = acc[i][j];
                if (BIAS) v += bias[n];
                if (RES)  v += res[(size_t)m * N + n];
                if (RELU) v = fmaxf(v, 0.f);
                store1(&C[(size_t)m * N + n], v);
            }
        }
    }
}

// ---------------- MFMA attention: one block (4 waves) per (b, head) -------------
__global__ __launch_bounds__(256) void attn_kernel(const u16* __restrict__ qkv,
                                                   u16* __restrict__ o)
{
    constexpr int QS = 40;
    constexpr int VS = 136;
    __shared__ __align__(16) u16 Qs[128 * QS];
    __shared__ __align__(16) u16 Ks[128 * QS];
    __shared__ __align__(16) u16 Vt[32 * VS];
    __shared__ __align__(16) u16 Ps[4][16 * VS];

    const int bh = blockIdx.x;
    const int b = bh >> 3, h = bh & 7;
    const int tid = threadIdx.x;
    const int w = tid >> 6, l = tid & 63;
    const int lg = l >> 4, li = l & 15;

    {
        u32* z1 = (u32*)Qs;
        for (int i = tid; i < 128 * QS / 2; i += 256) z1[i] = 0;
        u32* z2 = (u32*)Ks;
        for (int i = tid; i < 128 * QS / 2; i += 256) z2[i] = 0;
        u32* z3 = (u32*)Vt;
        for (int i = tid; i < 32 * VS / 2; i += 256) z3[i] = 0;
    }
    __syncthreads();

    const u32* q32 = (const u32*)(qkv + (size_t)b * T_ * TH_);
    for (int idx = tid; idx < 120 * 9; idx += 256) {
        int t = idx / 9, dp = idx - t * 9;
        u32 qv = q32[t * 216 + 9 * h + dp];
        u32 kv = q32[t * 216 + 72 + 9 * h + dp];
        u32 vv = q32[t * 216 + 144 + 9 * h + dp];
        ((u32*)(Qs + t * QS))[dp] = qv;
        ((u32*)(Ks + t * QS))[dp] = kv;
        Vt[(2 * dp) * VS + t]     = (u16)(vv & 0xffffu);
        Vt[(2 * dp + 1) * VS + t] = (u16)(vv >> 16);
    }
    __syncthreads();

    const float scale = 0.23570226039551584f; // 1/sqrt(18)
    u16* pw = &Ps[w][0];

    for (int mt = w * 2; mt < w * 2 + 2; ++mt) {
        short8v qf = *(const short8v*)(Qs + (mt * 16 + li) * QS + lg * 8);
        f32x4 sacc[8];
#pragma unroll
        for (int nt = 0; nt < 8; ++nt) sacc[nt] = {0.f, 0.f, 0.f, 0.f};
#pragma unroll
        for (int nt = 0; nt < 8; ++nt) {
            short8v kf = *(const short8v*)(Ks + (nt * 16 + li) * QS + lg * 8);
            sacc[nt] = __builtin_amdgcn_mfma_f32_16x16x32_bf16(qf, kf, sacc[nt], 0, 0, 0);
        }

        float invl[4];
#pragma unroll
        for (int j = 0; j < 4; ++j) {
            float v[8];
            float m = -1e30f;
#pragma unroll
            for (int nt = 0; nt < 8; ++nt) {
                float s = sacc[nt][j] * scale;
                if (nt == 7 && li >= 8) s = -1e30f;
                v[nt] = s;
                m = fmaxf(m, s);
            }
#pragma unroll
            for (int off = 1; off < 16; off <<= 1)
                m = fmaxf(m, __shfl_xor(m, off));
            float sum = 0.f;
#pragma unroll
            for (int nt = 0; nt < 8; ++nt) {
                float p = __expf(v[nt] - m);
                sum += p;
                pw[(lg * 4 + j) * VS + nt * 16 + li] = f2bf(p);
            }
#pragma unroll
            for (int off = 1; off < 16; off <<= 1)
                sum += __shfl_xor(sum, off);
            invl[j] = 1.f / sum;
        }

        f32x4 oacc[2] = {{0.f,0.f,0.f,0.f},{0.f,0.f,0.f,0.f}};
#pragma unroll
        for (int s = 0; s < 4; ++s) {
            short8v pf = *(const short8v*)(pw + li * VS + s * 32 + lg * 8);
#pragma unroll
            for (int dt = 0; dt < 2; ++dt) {
                short8v vf = *(const short8v*)(Vt + (dt * 16 + li) * VS + s * 32 + lg * 8);
                oacc[dt] = __builtin_amdgcn_mfma_f32_16x16x32_bf16(pf, vf, oacc[dt], 0, 0, 0);
            }
        }

        const int q0 = mt * 16 + lg * 4;
#pragma unroll
        for (int dt = 0; dt < 2; ++dt) {
            int d = dt * 16 + li;
            if (d < HD_) {
#pragma unroll
                for (int j = 0; j < 4; ++j) {
                    int q = q0 + j;
                    if (q < T_)
                        o[((size_t)b * T_ + q) * E_ + h * HD_ + d] =
                            f2bf(oacc[dt][j] * invl[j]);
                }
            }
        }
    }
}

// ---------------- mean over T (one chunk of nb batches) -------------------------
__global__ void mean_kernel(const float* __restrict__ x, float* __restrict__ out,
                            int nb)
{
    int idx = blockIdx.x * blockDim.x + threadIdx.x;
    if (idx >= nb * E_) return;
    int b = idx / E_, e = idx % E_;
    const float* p = x + (size_t)b * T_ * E_ + e;
    float s = 0.f;
    for (int t = 0; t < T_; t++) s += p[(size_t)t * E_];
    out[idx] = s * (1.f / 120.f);
}

__device__ __forceinline__ float sigmoidf_(float x) {
    return 1.f / (1.f + __expf(-x));
}

// ======== persistent GRU decode: all 24 steps in one kernel =====================
#define GRU_M 16
__global__ __launch_bounds__(192) void gru_all_kernel(
    const float* __restrict__ seed,      // inp0 = seed[:, T-1, :]
    const float* __restrict__ gctx,      // [B,432] ctx-half + b_ih
    const u16* __restrict__ WxB,         // [432,160] w_ih[:, :144] bf16
    const u16* __restrict__ WhB,         // [432,160] w_hh bf16
    const u16* __restrict__ SpB,         // [144,160] spl_w bf16
    const float* __restrict__ b_hh,
    const float* __restrict__ spl_b,
    float* __restrict__ out)             // [B, FUT, 144]
{
    __shared__ __align__(16) u16 xls[GRU_M * 168];
    __shared__ __align__(16) u16 hls[GRU_M * 168];

    const int tid = threadIdx.x;
    const int w = tid >> 6, l = tid & 63;
    const int lg = l >> 4, li = l & 15;
    const int b0 = blockIdx.x * GRU_M;
    const int fr = w * 48 + li;          // col base (+ct*16)

    for (int i = tid; i < GRU_M * 84; i += 192) {
        ((u32*)xls)[i] = 0; ((u32*)hls)[i] = 0;
    }
    __syncthreads();
    for (int i = tid; i < GRU_M * 72; i += 192) {
        int r = i / 72, e2 = i - r * 72;
        float2 t = *(const float2*)(seed + (size_t)(b0 + r) * T_ * E_
                                    + (size_t)(T_ - 1) * E_ + 2 * e2);
        ((u32*)(xls + r * 168))[e2] = ((u32)f2bf(t.y) << 16) | (u32)f2bf(t.x);
    }

    float gctxv[3][3][4];
    float bhh[3][3];
    float splb[3];
#pragma unroll
    for (int g = 0; g < 3; ++g)
#pragma unroll
        for (int ct = 0; ct < 3; ++ct) {
            int f = g * 144 + fr + ct * 16;
            bhh[g][ct] = b_hh[f];
#pragma unroll
            for (int j = 0; j < 4; ++j)
                gctxv[g][ct][j] = gctx[(size_t)(b0 + lg * 4 + j) * TH_ + f];
        }
#pragma unroll
    for (int ct = 0; ct < 3; ++ct) splb[ct] = spl_b[fr + ct * 16];

    float hold[3][4];
#pragma unroll
    for (int ct = 0; ct < 3; ++ct)
#pragma unroll
        for (int j = 0; j < 4; ++j) hold[ct][j] = 0.f;

    __syncthreads();

    for (int st = 0; st < FUT_; ++st) {
        f32x4 aRZ[2][3], aNi[3], aNh[3];
#pragma unroll
        for (int g = 0; g < 2; ++g)
#pragma unroll
            for (int ct = 0; ct < 3; ++ct) aRZ[g][ct] = {0.f, 0.f, 0.f, 0.f};
#pragma unroll
        for (int ct = 0; ct < 3; ++ct) {
            aNi[ct] = {0.f, 0.f, 0.f, 0.f};
            aNh[ct] = {0.f, 0.f, 0.f, 0.f};
        }
#pragma unroll
        for (int s = 0; s < 5; ++s) {
            short8v ax = *(const short8v*)(xls + li * 168 + s * 32 + lg * 8);
            short8v ah = *(const short8v*)(hls + li * 168 + s * 32 + lg * 8);
#pragma unroll
            for (int ct = 0; ct < 3; ++ct) {
#pragma unroll
                for (int g = 0; g < 2; ++g) {
                    int f = g * 144 + fr + ct * 16;
                    short8v bx = *(const short8v*)(WxB + (size_t)f * 160 + s * 32 + lg * 8);
                    aRZ[g][ct] = __builtin_amdgcn_mfma_f32_16x16x32_bf16(ax, bx, aRZ[g][ct], 0, 0, 0);
                    short8v bh = *(const short8v*)(WhB + (size_t)f * 160 + s * 32 + lg * 8);
                    aRZ[g][ct] = __builtin_amdgcn_mfma_f32_16x16x32_bf16(ah, bh, aRZ[g][ct], 0, 0, 0);
                }
                int f2 = 288 + fr + ct * 16;
                short8v bx2 = *(const short8v*)(WxB + (size_t)f2 * 160 + s * 32 + lg * 8);
                aNi[ct] = __builtin_amdgcn_mfma_f32_16x16x32_bf16(ax, bx2, aNi[ct], 0, 0, 0);
                short8v bh2 = *(const short8v*)(WhB + (size_t)f2 * 160 + s * 32 + lg * 8);
                aNh[ct] = __builtin_amdgcn_mfma_f32_16x16x32_bf16(ah, bh2, aNh[ct], 0, 0, 0);
            }
        }
        __syncthreads();   // all xls/hls reads retired before hls overwrite
#pragma unroll
        for (int ct = 0; ct < 3; ++ct)
#pragma unroll
            for (int j = 0; j < 4; ++j) {
                float r = sigmoidf_(aRZ[0][ct][j] + gctxv[0][ct][j] + bhh[0][ct]);
                float z = sigmoidf_(aRZ[1][ct][j] + gctxv[1][ct][j] + bhh[1][ct]);
                float n = tanhf(aNi[ct][j] + gctxv[2][ct][j]
                                + r * (aNh[ct][j] + bhh[2][ct]));
                float hv = (1.f - z) * n + z * hold[ct][j];
                hold[ct][j] = hv;
                hls[(lg * 4 + j) * 168 + fr + ct * 16] = f2bf(hv);
            }
        __syncthreads();
        // spl projection: rot = h_new @ spl^T + spl_b
        f32x4 aS[3];
#pragma unroll
        for (int ct = 0; ct < 3; ++ct) aS[ct] = {0.f, 0.f, 0.f, 0.f};
#pragma unroll
        for (int s = 0; s < 5; ++s) {
            short8v ah = *(const short8v*)(hls + li * 168 + s * 32 + lg * 8);
#pragma unroll
            for (int ct = 0; ct < 3; ++ct) {
                short8v bs = *(const short8v*)(SpB + (size_t)(fr + ct * 16) * 160 + s * 32 + lg * 8);
                aS[ct] = __builtin_amdgcn_mfma_f32_16x16x32_bf16(ah, bs, aS[ct], 0, 0, 0);
            }
        }
#pragma unroll
        for (int ct = 0; ct < 3; ++ct) {
            int col = fr + ct * 16;
#pragma unroll
            for (int j = 0; j < 4; ++j) {
                float rv = aS[ct][j] + splb[ct];
                out[(size_t)(b0 + lg * 4 + j) * (FUT_ * E_) + (size_t)st * E_ + col] = rv;
                xls[(lg * 4 + j) * 168 + col] = f2bf(rv);   // next step's input
            }
        }
        __syncthreads();
    }
}

// =================================================================================
extern "C" void kernel_launch(void* const* d_in, const int* in_sizes, int n_in,
                              void* d_out, int out_size, void* d_ws, size_t ws_size,
                              hipStream_t stream)
{
    const float* seed   = (const float*)d_in[0];
    const float* qkv_w  = (const float*)d_in[1];
    const float* qkv_b  = (const float*)d_in[2];
    const float* out_w  = (const float*)d_in[3];
    const float* out_b  = (const float*)d_in[4];
    const float* ln1_w  = (const float*)d_in[5];
    const float* ln1_b  = (const float*)d_in[6];
    const float* ffn1_w = (const float*)d_in[7];
    const float* ffn1_b = (const float*)d_in[8];
    const float* ffn2_w = (const float*)d_in[9];
    const float* ffn2_b = (const float*)d_in[10];
    const float* ln2_w  = (const float*)d_in[11];
    const float* ln2_b  = (const float*)d_in[12];
    const float* proj_w = (const float*)d_in[13];
    const float* proj_b = (const float*)d_in[14];
    const float* w_ih   = (const float*)d_in[15];
    const float* w_hh   = (const float*)d_in[16];
    const float* b_ih   = (const float*)d_in[17];
    const float* b_hh   = (const float*)d_in[18];
    const float* spl_w  = (const float*)d_in[19];
    const float* spl_b  = (const float*)d_in[20];

    // bf16 padded weight copies
    const size_t qkvW_n  = (size_t)L_ * TH_ * 160;
    const size_t outW_n  = (size_t)L_ * E_ * 160;
    const size_t ffn1W_n = (size_t)L_ * FF_ * 160;
    const size_t ffn2W_n = (size_t)L_ * E_ * 576;
    const size_t wxW_n   = (size_t)TH_ * 160;
    const size_t whW_n   = (size_t)TH_ * 160;
    const size_t spW_n   = (size_t)E_ * 160;
    const size_t wbytes  = (qkvW_n + outW_n + ffn1W_n + ffn2W_n
                            + wxW_n + whW_n + spW_n) * 2;

    const size_t persist = (size_t)B_ * 4 * (E_ + E_ + TH_) + wbytes;

    // per-chunk bytes/row: xbf(288) + xres(576) + qf(864) + ob(288) = 2016
    int nc = 16;
    for (int c = 1; c <= 16; c <<= 1) {
        size_t rows = (size_t)(B_ / c) * T_;
        size_t need = persist + rows * 2016;
        if (need <= ws_size) { nc = c; break; }
    }
    const int BC = B_ / nc;
    const int CR = BC * T_;

    char* wsp = (char*)d_ws;
    u16*   xbf   = (u16*)wsp;   wsp += (size_t)CR * E_ * 2;
    float* xres  = (float*)wsp; wsp += (size_t)CR * E_ * 4;
    u16*   qf    = (u16*)wsp;   wsp += (size_t)CR * TH_ * 2;
    u16*   ob    = (u16*)wsp;   wsp += (size_t)CR * E_ * 2;
    float* ctxm  = (float*)wsp; wsp += (size_t)B_ * E_ * 4;
    float* ctx   = (float*)wsp; wsp += (size_t)B_ * E_ * 4;
    float* gctx  = (float*)wsp; wsp += (size_t)B_ * TH_ * 4;
    u16* qkvWb   = (u16*)wsp;   wsp += qkvW_n * 2;
    u16* outWb   = (u16*)wsp;   wsp += outW_n * 2;
    u16* ffn1Wb  = (u16*)wsp;   wsp += ffn1W_n * 2;
    u16* ffn2Wb  = (u16*)wsp;   wsp += ffn2W_n * 2;
    u16* wxB     = (u16*)wsp;   wsp += wxW_n * 2;
    u16* whB     = (u16*)wsp;   wsp += whW_n * 2;
    u16* splWb   = (u16*)wsp;   wsp += spW_n * 2;

    wconv_kernel<<<(int)((qkvW_n + 255) / 256), 256, 0, stream>>>(qkv_w, qkvWb, L_ * TH_, 144, 160, 144);
    wconv_kernel<<<(int)((outW_n + 255) / 256), 256, 0, stream>>>(out_w, outWb, L_ * E_, 144, 160, 144);
    wconv_kernel<<<(int)((ffn1W_n + 255) / 256), 256, 0, stream>>>(ffn1_w, ffn1Wb, L_ * FF_, 144, 160, 144);
    wconv_kernel<<<(int)((ffn2W_n + 255) / 256), 256, 0, stream>>>(ffn2_w, ffn2Wb, L_ * E_, 576, 576, 576);
    wconv_kernel<<<(int)((wxW_n + 255) / 256), 256, 0, stream>>>(w_ih, wxB, TH_, 144, 160, GIN_);
    wconv_kernel<<<(int)((whW_n + 255) / 256), 256, 0, stream>>>(w_hh, whB, TH_, 144, 160, 144);
    wconv_kernel<<<(int)((spW_n + 255) / 256), 256, 0, stream>>>(spl_w, splWb, E_, 144, 160, 144);

    auto grid = [](int M, int N) { return dim3((N + 63) / 64, M / 64); };

    for (int c = 0; c < nc; c++) {
        const int b0 = c * BC;
        cast_bf_kernel<<<(CR * 72 + 255) / 256, 256, 0, stream>>>(
            seed + (size_t)b0 * T_ * E_, xbf, CR * 72);
        const float* resIn = seed + (size_t)b0 * T_ * E_;
        for (int l = 0; l < L_; l++) {
            gemm_mfma<u16><<<dim3(3, CR / 64), 192, 0, stream>>>(
                xbf, qkvWb + (size_t)l * TH_ * 160, qkv_b + (size_t)l * TH_,
                qf, CR, TH_);
            attn_kernel<<<BC * NH_, 256, 0, stream>>>(qf, ob);
            olnffn_kernel<<<CR / 64, 192, 0, stream>>>(
                ob, outWb + (size_t)l * E_ * 160, out_b + (size_t)l * E_, resIn,
                ln1_w + (size_t)l * E_, ln1_b + (size_t)l * E_,
                ffn1Wb + (size_t)l * FF_ * 160, ffn1_b + (size_t)l * FF_,
                ffn2Wb + (size_t)l * E_ * 576, ffn2_b + (size_t)l * E_,
                ln2_w + (size_t)l * E_, ln2_b + (size_t)l * E_, xbf, xres);
            resIn = xres;
        }
        mean_kernel<<<(BC * E_ + 255) / 256, 256, 0, stream>>>(xres, ctxm + (size_t)b0 * E_, BC);
    }

    gemm_kernel<float, float, true, false, false><<<grid(B_, E_), 256, 0, stream>>>(
        ctxm, proj_w, E_, proj_b, nullptr, ctx, B_, E_, E_);
    gemm_kernel<float, float, true, false, false><<<grid(B_, TH_), 256, 0, stream>>>(
        ctx, w_ih + E_, GIN_, b_ih, nullptr, gctx, B_, TH_, E_);

    gru_all_kernel<<<B_ / GRU_M, 192, 0, stream>>>(
        seed, gctx, wxB, whB, splWb, b_hh, spl_b, (float*)d_out);
}